// Round 10
// baseline (4848.325 us; speedup 1.0000x reference)
//
#include <hip/hip_runtime.h>

// Sinkhorn-log barycentric mapping, N=M=8192, D=128, reg=0.05, 50 iters.
// d_out layout: [ mapped: N*D f32 | pi: N*M f32 ].
// Big-ws path: Mr built by split-bf16 MFMA GEMM, quantized IN PLACE to
// per-row affine int16 (codes at bytes [0,16384) of each 32 KB row slot,
// (base,step) at byte 16384). 100 iteration passes read int16 (134 MB,
// L3-resident), nat-domain online LSE (round-7 proven config).
// part (128x8192) in mapped region (out+0), dead before mapped written.
// u,v,xx,yy + bf16 XQT in d_ws. Final fused kernel (512 blk x 256 thr)
// expands pi=exp(dec+u+v) in DECREASING column order and computes
// mapped = 8192*pi@XQ via bf16 MFMA.

#define NN 8192
#define MMX 8192
#define DD 128
#define NITER 50
#define LOGAB (-9.0109133472792881f)   /* log(1/8192) */
#define NEG20 (-20.0f)                 /* -1/reg */

typedef short bf16x8 __attribute__((ext_vector_type(8)));
typedef float f32x4 __attribute__((ext_vector_type(4)));
typedef unsigned short ushort_t;

static __device__ __forceinline__ void lse_acc(float& m, float& s, float x) {
    float mn = fmaxf(m, x);
    s = s * __expf(m - mn) + __expf(x - mn);
    m = mn;
}
static __device__ __forceinline__ void lse_merge(float& m, float& s, float m2, float s2) {
    float mn = fmaxf(m, m2);
    s = s * __expf(m - mn) + s2 * __expf(m2 - mn);
    m = mn;
}
static __device__ __forceinline__ void lse_acc4(float4& m, float4& s, float4 x) {
    lse_acc(m.x, s.x, x.x);
    lse_acc(m.y, s.y, x.y);
    lse_acc(m.z, s.z, x.z);
    lse_acc(m.w, s.w, x.w);
}
static __device__ __forceinline__ int swz(int r, int k) {
    return k ^ (((r >> 3) & 7) << 2);
}
static __device__ __forceinline__ unsigned f2bf(float x) {
    unsigned u = __float_as_uint(x);
    return (u + 0x7FFF + ((u >> 16) & 1)) >> 16;   // RNE
}
static __device__ __forceinline__ float4 dec4(uint2 w, float stp, float bas) {
    float4 o;
    o.x = (float)(w.x & 0xFFFFu) * stp + bas;
    o.y = (float)(w.x >> 16)     * stp + bas;
    o.z = (float)(w.y & 0xFFFFu) * stp + bas;
    o.w = (float)(w.y >> 16)     * stp + bas;
    return o;
}
// split f32x4 -> hi bf16x4 + lo bf16x4 (packed)
static __device__ __forceinline__ uint2 packhl(float4 x, uint2& lo) {
    unsigned h0 = f2bf(x.x), h1 = f2bf(x.y), h2 = f2bf(x.z), h3 = f2bf(x.w);
    float r0 = x.x - __uint_as_float(h0 << 16);
    float r1 = x.y - __uint_as_float(h1 << 16);
    float r2 = x.z - __uint_as_float(h2 << 16);
    float r3 = x.w - __uint_as_float(h3 << 16);
    lo = make_uint2(f2bf(r0) | (f2bf(r1) << 16), f2bf(r2) | (f2bf(r3) << 16));
    return make_uint2(h0 | (h1 << 16), h2 | (h3 << 16));
}

// ---- zero u, v --------------------------------------------------------------
__global__ void k_init(float* u, float* v) {
    int i = blockIdx.x * 1024 + threadIdx.x;
    if (i < 8192) { u[i] = 0.0f; v[i] = 0.0f; }
}

// ---- squared norms ----------------------------------------------------------
__global__ __launch_bounds__(64) void k_sqnorm(const float* __restrict__ XP,
                                               const float* __restrict__ XQ,
                                               float* __restrict__ xx,
                                               float* __restrict__ yy) {
    int row = blockIdx.x;
    int lane = threadIdx.x;
    const float* src = (row < NN) ? (XP + (size_t)row * DD)
                                  : (XQ + (size_t)(row - NN) * DD);
    float2 w = *(const float2*)&src[lane * 2];
    float sres = w.x * w.x + w.y * w.y;
    #pragma unroll
    for (int off = 32; off > 0; off >>= 1)
        sres += __shfl_down(sres, off, 64);
    if (lane == 0) {
        if (row < NN) xx[row] = sres;
        else          yy[row - NN] = sres;
    }
}

// ---- XQT[d][m] = bf16(XQ[m][d]) ---------------------------------------------
__global__ __launch_bounds__(256) void k_xqt(const float* __restrict__ XQ,
                                             unsigned* __restrict__ XQT32) {
    __shared__ float As[32][129];
    int mb = blockIdx.x * 32;
    int t = threadIdx.x;
    int r = t >> 3, c0 = (t & 7) * 16;
    #pragma unroll
    for (int j = 0; j < 4; ++j)
        *(float4*)&As[r][c0 + j * 4] = *(const float4*)&XQ[(size_t)(mb + r) * DD + c0 + j * 4];
    __syncthreads();
    int d = t >> 1, p0 = (t & 1) * 8;
    #pragma unroll
    for (int j = 0; j < 8; ++j) {
        int pp = p0 + j;
        unsigned lo = f2bf(As[2 * pp][d]);
        unsigned hi = f2bf(As[2 * pp + 1][d]);
        XQT32[(size_t)d * 4096 + (mb >> 1) + pp] = lo | (hi << 16);
    }
}

// ---- MFMA Mr GEMM: Mr = -20*max(0, xx+yy-2*(hh+hl+lh)) ----------------------
__global__ __launch_bounds__(256, 2) void k_gemm_mr_mfma(const float* __restrict__ XP,
                                                         const float* __restrict__ XQ,
                                                         const float* __restrict__ xx,
                                                         const float* __restrict__ yy,
                                                         float* __restrict__ Mr) {
    __shared__ ushort_t Ah[128 * 64], Al[128 * 64];
    __shared__ ushort_t Bh[128 * 64], Bl[128 * 64];
    int rb = blockIdx.y * 128, cb = blockIdx.x * 128;
    int t = threadIdx.x;
    int w = t >> 6, lane = t & 63;
    int lane15 = lane & 15, lhi = lane >> 4;
    int wr = (w >> 1) * 64, wc = (w & 1) * 64;

    f32x4 acc00 = (f32x4)(0.f), acc01 = acc00, acc02 = acc00, acc03 = acc00;
    f32x4 acc10 = acc00, acc11 = acc00, acc12 = acc00, acc13 = acc00;
    f32x4 acc20 = acc00, acc21 = acc00, acc22 = acc00, acc23 = acc00;
    f32x4 acc30 = acc00, acc31 = acc00, acc32 = acc00, acc33 = acc00;

    for (int kc = 0; kc < 128; kc += 64) {
        __syncthreads();
        #pragma unroll
        for (int i = 0; i < 8; ++i) {
            int f = i * 256 + t;
            int r = f >> 4;
            int k4 = (f & 15) * 4;
            int g = k4 >> 3, hf = (k4 >> 2) & 1;
            int wa = r * 64 + ((g ^ (r & 7)) * 8 + hf * 4);
            float4 a = *(const float4*)&XP[(size_t)(rb + r) * DD + kc + k4];
            float4 b = *(const float4*)&XQ[(size_t)(cb + r) * DD + kc + k4];
            uint2 alo, blo;
            uint2 ahi = packhl(a, alo);
            uint2 bhi = packhl(b, blo);
            *(uint2*)&Ah[wa] = ahi; *(uint2*)&Al[wa] = alo;
            *(uint2*)&Bh[wa] = bhi; *(uint2*)&Bl[wa] = blo;
        }
        __syncthreads();
        #pragma unroll
        for (int ks = 0; ks < 2; ++ks) {
            int g = ks * 4 + lhi;
            bf16x8 ah[4], al[4], bh[4], bl[4];
            #pragma unroll
            for (int i = 0; i < 4; ++i) {
                int ar = wr + i * 16 + lane15;
                int ao = ar * 64 + ((g ^ (ar & 7)) * 8);
                ah[i] = *(bf16x8*)&Ah[ao];
                al[i] = *(bf16x8*)&Al[ao];
                int br = wc + i * 16 + lane15;
                int bo = br * 64 + ((g ^ (br & 7)) * 8);
                bh[i] = *(bf16x8*)&Bh[bo];
                bl[i] = *(bf16x8*)&Bl[bo];
            }
            #define MM3(AC, I, J) \
                AC = __builtin_amdgcn_mfma_f32_16x16x32_bf16(ah[I], bh[J], AC, 0, 0, 0); \
                AC = __builtin_amdgcn_mfma_f32_16x16x32_bf16(ah[I], bl[J], AC, 0, 0, 0); \
                AC = __builtin_amdgcn_mfma_f32_16x16x32_bf16(al[I], bh[J], AC, 0, 0, 0);
            MM3(acc00,0,0) MM3(acc01,0,1) MM3(acc02,0,2) MM3(acc03,0,3)
            MM3(acc10,1,0) MM3(acc11,1,1) MM3(acc12,1,2) MM3(acc13,1,3)
            MM3(acc20,2,0) MM3(acc21,2,1) MM3(acc22,2,2) MM3(acc23,2,3)
            MM3(acc30,3,0) MM3(acc31,3,1) MM3(acc32,3,2) MM3(acc33,3,3)
            #undef MM3
        }
    }
    float yv[4];
    #pragma unroll
    for (int j = 0; j < 4; ++j) yv[j] = yy[cb + wc + j * 16 + lane15];
    #define EPI(AC, I, J) { \
        _Pragma("unroll") \
        for (int reg = 0; reg < 4; ++reg) { \
            int gr = rb + wr + I * 16 + lhi * 4 + reg; \
            float C = xx[gr] + yv[J] - 2.f * AC[reg]; \
            Mr[(size_t)gr * MMX + cb + wc + J * 16 + lane15] = NEG20 * fmaxf(C, 0.f); \
        } }
    EPI(acc00,0,0) EPI(acc01,0,1) EPI(acc02,0,2) EPI(acc03,0,3)
    EPI(acc10,1,0) EPI(acc11,1,1) EPI(acc12,1,2) EPI(acc13,1,3)
    EPI(acc20,2,0) EPI(acc21,2,1) EPI(acc22,2,2) EPI(acc23,2,3)
    EPI(acc30,3,0) EPI(acc31,3,1) EPI(acc32,3,2) EPI(acc33,3,3)
    #undef EPI
}

// ---- f32 vector Mr GEMM (fallback paths only) --------------------------------
__global__ __launch_bounds__(256) void k_gemm_mr(const float* __restrict__ XP,
                                                 const float* __restrict__ XQ,
                                                 const float* __restrict__ xx,
                                                 const float* __restrict__ yy,
                                                 float* __restrict__ Mr) {
    __shared__ float As[128][64];
    __shared__ float Bs[128][64];
    int rb = blockIdx.y * 128, cb = blockIdx.x * 128;
    int t = threadIdx.x;
    int ty = t >> 4, tx = t & 15;
    int r0 = ty * 8, c0 = tx * 8;
    float acc[8][8] = {};

    for (int kc = 0; kc < 128; kc += 64) {
        __syncthreads();
        #pragma unroll
        for (int i = 0; i < 8; ++i) {
            int f = i * 256 + t;
            int r = f >> 4;
            int k4 = (f & 15) * 4;
            *(float4*)&As[r][swz(r, k4)] = *(const float4*)&XP[(size_t)(rb + r) * DD + kc + k4];
            *(float4*)&Bs[r][swz(r, k4)] = *(const float4*)&XQ[(size_t)(cb + r) * DD + kc + k4];
        }
        __syncthreads();
        for (int k = 0; k < 64; k += 4) {
            float4 a[8], b[8];
            #pragma unroll
            for (int i = 0; i < 8; ++i) {
                a[i] = *(float4*)&As[r0 + i][swz(r0 + i, k)];
                b[i] = *(float4*)&Bs[c0 + i][swz(c0 + i, k)];
            }
            #pragma unroll
            for (int i = 0; i < 8; ++i)
                #pragma unroll
                for (int j = 0; j < 8; ++j)
                    acc[i][j] += a[i].x * b[j].x + a[i].y * b[j].y +
                                 a[i].z * b[j].z + a[i].w * b[j].w;
        }
    }

    float yv[8];
    *(float4*)&yv[0] = *(const float4*)&yy[cb + c0];
    *(float4*)&yv[4] = *(const float4*)&yy[cb + c0 + 4];
    #pragma unroll
    for (int i = 0; i < 8; ++i) {
        int gr = rb + r0 + i;
        float xxi = xx[gr];
        float4 o0, o1;
        o0.x = NEG20 * fmaxf(xxi + yv[0] - 2.f * acc[i][0], 0.f);
        o0.y = NEG20 * fmaxf(xxi + yv[1] - 2.f * acc[i][1], 0.f);
        o0.z = NEG20 * fmaxf(xxi + yv[2] - 2.f * acc[i][2], 0.f);
        o0.w = NEG20 * fmaxf(xxi + yv[3] - 2.f * acc[i][3], 0.f);
        o1.x = NEG20 * fmaxf(xxi + yv[4] - 2.f * acc[i][4], 0.f);
        o1.y = NEG20 * fmaxf(xxi + yv[5] - 2.f * acc[i][5], 0.f);
        o1.z = NEG20 * fmaxf(xxi + yv[6] - 2.f * acc[i][6], 0.f);
        o1.w = NEG20 * fmaxf(xxi + yv[7] - 2.f * acc[i][7], 0.f);
        *(float4*)&Mr[(size_t)gr * MMX + cb + c0] = o0;
        *(float4*)&Mr[(size_t)gr * MMX + cb + c0 + 4] = o1;
    }
}

// ---- quantize Mr row -> in-slot int16 + (base,step) --------------------------
__global__ __launch_bounds__(256) void k_quant(float* __restrict__ Mr) {
    float* slot = Mr + (size_t)blockIdx.x * MMX;
    int t = threadIdx.x;
    float4 x[8];
    float mn = 1e30f, mx = -1e30f;
    #pragma unroll
    for (int i = 0; i < 8; ++i) {
        x[i] = *(const float4*)&slot[(t + 256 * i) * 4];
        mn = fminf(mn, fminf(fminf(x[i].x, x[i].y), fminf(x[i].z, x[i].w)));
        mx = fmaxf(mx, fmaxf(fmaxf(x[i].x, x[i].y), fmaxf(x[i].z, x[i].w)));
    }
    #pragma unroll
    for (int off = 32; off > 0; off >>= 1) {
        mn = fminf(mn, __shfl_xor(mn, off));
        mx = fmaxf(mx, __shfl_xor(mx, off));
    }
    __shared__ float smn[4], smx[4];
    int wid = t >> 6;
    if ((t & 63) == 0) { smn[wid] = mn; smx[wid] = mx; }
    __syncthreads();
    mn = fminf(fminf(smn[0], smn[1]), fminf(smn[2], smn[3]));
    mx = fmaxf(fmaxf(smx[0], smx[1]), fmaxf(smx[2], smx[3]));
    float span = fmaxf(mx - mn, 1e-20f);
    float inv = 65535.0f / span;
    float stp = span * (1.0f / 65535.0f);
    uint2* out16 = (uint2*)slot;
    #pragma unroll
    for (int i = 0; i < 8; ++i) {
        unsigned q0 = (unsigned)fminf(rintf((x[i].x - mn) * inv), 65535.f);
        unsigned q1 = (unsigned)fminf(rintf((x[i].y - mn) * inv), 65535.f);
        unsigned q2 = (unsigned)fminf(rintf((x[i].z - mn) * inv), 65535.f);
        unsigned q3 = (unsigned)fminf(rintf((x[i].w - mn) * inv), 65535.f);
        out16[t + 256 * i] = make_uint2(q0 | (q1 << 16), q2 | (q3 << 16));
    }
    if (t == 0) *(float2*)&slot[4096] = make_float2(mn, stp);
}

// ---- column-LSE partial (round-7 proven): (8,128) grid, 1024 cols x 64 rows --
__global__ __launch_bounds__(256) void k_colpass_q64(const float* __restrict__ Mr,
                                                     const float* __restrict__ u,
                                                     float* __restrict__ part) {
    int c = blockIdx.x * 1024 + threadIdx.x * 4;
    int n0 = blockIdx.y * 64;
    float4 mx = make_float4(-1e30f, -1e30f, -1e30f, -1e30f);
    float4 s = make_float4(0.f, 0.f, 0.f, 0.f);
    #pragma unroll 8
    for (int r = 0; r < 64; ++r) {
        const float* slot = Mr + (size_t)(n0 + r) * MMX;
        float2 bs = *(const float2*)&slot[4096];
        float basu = bs.x + u[n0 + r];
        uint2 w = *(const uint2*)((const ushort_t*)slot + c);
        lse_acc4(mx, s, dec4(w, bs.y, basu));
    }
    float4 o;
    o.x = mx.x + __logf(s.x);
    o.y = mx.y + __logf(s.y);
    o.z = mx.z + __logf(s.z);
    o.w = mx.w + __logf(s.w);
    *(float4*)&part[(size_t)blockIdx.y * MMX + c] = o;
}

// ---- combine 128 chunk-LSEs -> v[m], 2-way split chain -----------------------
__global__ __launch_bounds__(256) void k_colcombine128(const float* __restrict__ part,
                                                       float* __restrict__ v) {
    int t = threadIdx.x;
    int col = blockIdx.x * 128 + (t & 127);
    int half = t >> 7;
    float mx = -1e30f, s = 0.f;
    #pragma unroll 8
    for (int ch = 0; ch < 64; ++ch)
        lse_acc(mx, s, part[(size_t)(half * 64 + ch) * MMX + col]);
    __shared__ float sm[256];
    if (half) { sm[t & 127] = mx; sm[128 + (t & 127)] = s; }
    __syncthreads();
    if (!half) {
        lse_merge(mx, s, sm[t], sm[128 + t]);
        v[col] = LOGAB - (mx + __logf(s));
    }
}

// ---- row-LSE (round-7 proven): 1024 blocks x 8 rows, + unroll-2 pipeline -----
__global__ __launch_bounds__(256) void k_rowpass_q(const float* __restrict__ Mr,
                                                   const float* __restrict__ v,
                                                   float* __restrict__ u) {
    int n0 = blockIdx.x * 8;
    int t = threadIdx.x;
    float basr[8], stpr[8];
    const ushort_t* us[8];
    #pragma unroll
    for (int r = 0; r < 8; ++r) {
        const float* slot = Mr + (size_t)(n0 + r) * MMX;
        float2 bs = *(const float2*)&slot[4096];
        basr[r] = bs.x;
        stpr[r] = bs.y;
        us[r] = (const ushort_t*)slot;
    }
    float4 mx[8], s[8];
    #pragma unroll
    for (int r = 0; r < 8; ++r) {
        mx[r] = make_float4(-1e30f, -1e30f, -1e30f, -1e30f);
        s[r] = make_float4(0.f, 0.f, 0.f, 0.f);
    }
    const float4* v4 = (const float4*)v;
    #pragma unroll 2
    for (int i = t; i < MMX / 4; i += 256) {
        float4 vv = v4[i];
        #pragma unroll
        for (int r = 0; r < 8; ++r) {
            uint2 w = *(const uint2*)&us[r][i * 4];
            float4 d = dec4(w, stpr[r], basr[r]);
            d.x += vv.x; d.y += vv.y; d.z += vv.z; d.w += vv.w;
            lse_acc4(mx[r], s[r], d);
        }
    }
    __shared__ float smm[8][4], sss[8][4];
    int wid = t >> 6, lane = t & 63;
    #pragma unroll
    for (int r = 0; r < 8; ++r) {
        float m1 = mx[r].x, s1 = s[r].x;
        lse_merge(m1, s1, mx[r].y, s[r].y);
        lse_merge(m1, s1, mx[r].z, s[r].z);
        lse_merge(m1, s1, mx[r].w, s[r].w);
        #pragma unroll
        for (int off = 32; off > 0; off >>= 1) {
            float m2 = __shfl_xor(m1, off);
            float s2 = __shfl_xor(s1, off);
            lse_merge(m1, s1, m2, s2);
        }
        if (lane == 0) { smm[r][wid] = m1; sss[r][wid] = s1; }
    }
    __syncthreads();
    if (t < 8) {
        float m1 = smm[t][0], s1 = sss[t][0];
        lse_merge(m1, s1, smm[t][1], sss[t][1]);
        lse_merge(m1, s1, smm[t][2], sss[t][2]);
        lse_merge(m1, s1, smm[t][3], sss[t][3]);
        u[n0 + t] = LOGAB - (m1 + __logf(s1));
    }
}

// ---- f32 colpass/combine/rowpass (fallback paths) ----------------------------
__global__ __launch_bounds__(256) void k_colpass(const float* __restrict__ Mr,
                                                 const float* __restrict__ u,
                                                 float* __restrict__ part) {
    int c = blockIdx.x * 1024 + threadIdx.x * 4;
    int n0 = blockIdx.y * 128;
    float4 mx = make_float4(-1e30f, -1e30f, -1e30f, -1e30f);
    float4 s = make_float4(0.f, 0.f, 0.f, 0.f);
    #pragma unroll 8
    for (int r = 0; r < 128; ++r) {
        float un = u[n0 + r];
        float4 w = *(const float4*)&Mr[(size_t)(n0 + r) * MMX + c];
        w.x += un; w.y += un; w.z += un; w.w += un;
        lse_acc4(mx, s, w);
    }
    float4 o;
    o.x = mx.x + __logf(s.x);
    o.y = mx.y + __logf(s.y);
    o.z = mx.z + __logf(s.z);
    o.w = mx.w + __logf(s.w);
    *(float4*)&part[(size_t)blockIdx.y * MMX + c] = o;
}

__global__ __launch_bounds__(256) void k_colcombine(const float* __restrict__ part,
                                                    float* __restrict__ v) {
    int m = blockIdx.x * 256 + threadIdx.x;
    float mx = -1e30f, s = 0.f;
    #pragma unroll 8
    for (int ch = 0; ch < 64; ++ch)
        lse_acc(mx, s, part[(size_t)ch * MMX + m]);
    v[m] = LOGAB - (mx + __logf(s));
}

__global__ __launch_bounds__(256) void k_rowpass(const float* __restrict__ Mr,
                                                 const float* __restrict__ v,
                                                 float* __restrict__ u) {
    int n0 = blockIdx.x * 8;
    int t = threadIdx.x;
    float4 mx[8], s[8];
    #pragma unroll
    for (int r = 0; r < 8; ++r) {
        mx[r] = make_float4(-1e30f, -1e30f, -1e30f, -1e30f);
        s[r] = make_float4(0.f, 0.f, 0.f, 0.f);
    }
    const float4* v4 = (const float4*)v;
    for (int i = t; i < MMX / 4; i += 256) {
        float4 vv = v4[i];
        #pragma unroll
        for (int r = 0; r < 8; ++r) {
            float4 w = *(const float4*)&Mr[(size_t)(n0 + r) * MMX + i * 4];
            w.x += vv.x; w.y += vv.y; w.z += vv.z; w.w += vv.w;
            lse_acc4(mx[r], s[r], w);
        }
    }
    __shared__ float smm[8][4], sss[8][4];
    int wid = t >> 6, lane = t & 63;
    #pragma unroll
    for (int r = 0; r < 8; ++r) {
        float m1 = mx[r].x, s1 = s[r].x;
        lse_merge(m1, s1, mx[r].y, s[r].y);
        lse_merge(m1, s1, mx[r].z, s[r].z);
        lse_merge(m1, s1, mx[r].w, s[r].w);
        #pragma unroll
        for (int off = 32; off > 0; off >>= 1) {
            float m2 = __shfl_xor(m1, off);
            float s2 = __shfl_xor(s1, off);
            lse_merge(m1, s1, m2, s2);
        }
        if (lane == 0) { smm[r][wid] = m1; sss[r][wid] = s1; }
    }
    __syncthreads();
    if (t < 8) {
        float m1 = smm[t][0], s1 = sss[t][0];
        lse_merge(m1, s1, smm[t][1], sss[t][1]);
        lse_merge(m1, s1, smm[t][2], sss[t][2]);
        lse_merge(m1, s1, smm[t][3], sss[t][3]);
        u[n0 + t] = LOGAB - (m1 + __logf(s1));
    }
}

// ---- MFMA FUSED: 512 blocks x 256 thr x 16 rows. pi in place; mapped via MFMA.
__global__ __launch_bounds__(256) void k_pi_mapped_mfma_q(float* __restrict__ P,
                                                          const unsigned* __restrict__ XQT32,
                                                          const float* __restrict__ u,
                                                          const float* __restrict__ v,
                                                          float* __restrict__ mapped) {
    __shared__ unsigned short PIs[16 * 64];
    __shared__ unsigned short QTs[128 * 64];
    int r0 = blockIdx.x * 16;
    int t = threadIdx.x;                 // 0..255
    int wid = t >> 6, lane = t & 63;
    int lane15 = lane & 15, lhi = lane >> 4;
    int dbase = wid * 32;
    int prow = t >> 4;
    int pm4 = (t & 15) * 4;
    int pgran = (t & 15) >> 1, phalf = t & 1;
    int qd = t >> 1;
    int qg0 = (t & 1) * 4;

    float* slotp = P + (size_t)(r0 + prow) * MMX;
    const ushort_t* usp = (const ushort_t*)slotp;
    float2 bs = *(const float2*)&slotp[4096];
    float stp = bs.y;
    float basu = bs.x + u[r0 + prow];

    f32x4 acc[2];
    acc[0] = (f32x4)(0.f);
    acc[1] = (f32x4)(0.f);

    int mb0 = MMX - 64;
    uint2 pq = *(const uint2*)&usp[mb0 + pm4];
    float4 vv = *(const float4*)&v[mb0 + pm4];
    uint4 xq0 = *(const uint4*)&XQT32[(size_t)qd * 4096 + (mb0 >> 1) + qg0 * 4];
    uint4 xq1 = *(const uint4*)&XQT32[(size_t)qd * 4096 + (mb0 >> 1) + qg0 * 4 + 4];
    uint4 xq2 = *(const uint4*)&XQT32[(size_t)qd * 4096 + (mb0 >> 1) + qg0 * 4 + 8];
    uint4 xq3 = *(const uint4*)&XQT32[(size_t)qd * 4096 + (mb0 >> 1) + qg0 * 4 + 12];

    for (int mb = mb0; mb >= 0; mb -= 64) {
        __syncthreads();
        float4 d = dec4(pq, stp, basu);
        float4 w;
        w.x = __expf(d.x + vv.x);
        w.y = __expf(d.y + vv.y);
        w.z = __expf(d.z + vv.z);
        w.w = __expf(d.w + vv.w);
        uint2 pk;
        pk.x = f2bf(w.x) | (f2bf(w.y) << 16);
        pk.y = f2bf(w.z) | (f2bf(w.w) << 16);
        *(uint2*)&PIs[prow * 64 + (pgran ^ (prow & 7)) * 8 + phalf * 4] = pk;
        *(uint4*)&QTs[qd * 64 + ((qg0 + 0) ^ (qd & 7)) * 8] = xq0;
        *(uint4*)&QTs[qd * 64 + ((qg0 + 1) ^ (qd & 7)) * 8] = xq1;
        *(uint4*)&QTs[qd * 64 + ((qg0 + 2) ^ (qd & 7)) * 8] = xq2;
        *(uint4*)&QTs[qd * 64 + ((qg0 + 3) ^ (qd & 7)) * 8] = xq3;
        __syncthreads();
        *(float4*)&slotp[mb + pm4] = w;
        if (mb > 0) {
            int nb = mb - 64;
            pq = *(const uint2*)&usp[nb + pm4];
            vv = *(const float4*)&v[nb + pm4];
            xq0 = *(const uint4*)&XQT32[(size_t)qd * 4096 + (nb >> 1) + qg0 * 4];
            xq1 = *(const uint4*)&XQT32[(size_t)qd * 4096 + (nb >> 1) + qg0 * 4 + 4];
            xq2 = *(const uint4*)&XQT32[(size_t)qd * 4096 + (nb >> 1) + qg0 * 4 + 8];
            xq3 = *(const uint4*)&XQT32[(size_t)qd * 4096 + (nb >> 1) + qg0 * 4 + 12];
        }
        bf16x8 afr[2];
        #pragma unroll
        for (int ks = 0; ks < 2; ++ks) {
            int g = ks * 4 + lhi;
            afr[ks] = *(bf16x8*)&PIs[lane15 * 64 + (g ^ (lane15 & 7)) * 8];
        }
        #pragma unroll
        for (int dt = 0; dt < 2; ++dt) {
            int drow = dbase + dt * 16 + lane15;
            #pragma unroll
            for (int ks = 0; ks < 2; ++ks) {
                int g = ks * 4 + lhi;
                bf16x8 bfr = *(bf16x8*)&QTs[drow * 64 + (g ^ (drow & 7)) * 8];
                acc[dt] = __builtin_amdgcn_mfma_f32_16x16x32_bf16(afr[ks], bfr, acc[dt], 0, 0, 0);
            }
        }
    }
    #pragma unroll
    for (int dt = 0; dt < 2; ++dt) {
        int dcol = dbase + dt * 16 + lane15;
        #pragma unroll
        for (int reg = 0; reg < 4; ++reg) {
            int nrow = r0 + lhi * 4 + reg;
            mapped[(size_t)nrow * DD + dcol] = acc[dt][reg] * 8192.f;
        }
    }
}

// ---- vector FUSED (mid-ws path, f32 Mr) --------------------------------------
__global__ __launch_bounds__(512, 1) void k_pi_mapped(float* __restrict__ P,
                                                      const float* __restrict__ XQ,
                                                      const float* __restrict__ u,
                                                      const float* __restrict__ v,
                                                      float* __restrict__ mapped) {
    __shared__ float PIs[32][68];
    __shared__ float QS[64][128];
    int r0 = blockIdx.x * 32;
    int t = threadIdx.x;
    int tid = t & 255;
    int half = t >> 8;
    int rg = tid >> 5;
    int dg = tid & 31;
    int prow = t >> 4;
    int pc4 = (t & 15) * 4;
    int qrb = t >> 5;
    int qc4 = (t & 31) * 4;
    float urow = u[r0 + prow];

    float4 acc[4];
    acc[0] = acc[1] = acc[2] = acc[3] = make_float4(0.f, 0.f, 0.f, 0.f);

    float4 pw, vv, xq0, xq1, xq2, xq3;
    pw = *(const float4*)&P[(size_t)(r0 + prow) * MMX + pc4];
    vv = *(const float4*)&v[pc4];
    xq0 = *(const float4*)&XQ[(size_t)(qrb) * DD + qc4];
    xq1 = *(const float4*)&XQ[(size_t)(16 + qrb) * DD + qc4];
    xq2 = *(const float4*)&XQ[(size_t)(32 + qrb) * DD + qc4];
    xq3 = *(const float4*)&XQ[(size_t)(48 + qrb) * DD + qc4];

    for (int mb = 0; mb < MMX; mb += 64) {
        __syncthreads();
        float4 w;
        w.x = __expf(pw.x + urow + vv.x);
        w.y = __expf(pw.y + urow + vv.y);
        w.z = __expf(pw.z + urow + vv.z);
        w.w = __expf(pw.w + urow + vv.w);
        *(float4*)&PIs[prow][pc4] = w;
        *(float4*)&QS[qrb][qc4] = xq0;
        *(float4*)&QS[16 + qrb][qc4] = xq1;
        *(float4*)&QS[32 + qrb][qc4] = xq2;
        *(float4*)&QS[48 + qrb][qc4] = xq3;
        __syncthreads();
        *(float4*)&P[(size_t)(r0 + prow) * MMX + mb + pc4] = w;
        if (mb + 64 < MMX) {
            int nb = mb + 64;
            pw = *(const float4*)&P[(size_t)(r0 + prow) * MMX + nb + pc4];
            vv = *(const float4*)&v[nb + pc4];
            xq0 = *(const float4*)&XQ[(size_t)(nb + qrb) * DD + qc4];
            xq1 = *(const float4*)&XQ[(size_t)(nb + 16 + qrb) * DD + qc4];
            xq2 = *(const float4*)&XQ[(size_t)(nb + 32 + qrb) * DD + qc4];
            xq3 = *(const float4*)&XQ[(size_t)(nb + 48 + qrb) * DD + qc4];
        }
        #pragma unroll
        for (int sstep = 0; sstep < 8; ++sstep) {
            int k = (half * 8 + sstep) * 4;
            float4 q0 = *(float4*)&QS[k + 0][dg * 4];
            float4 q1 = *(float4*)&QS[k + 1][dg * 4];
            float4 q2 = *(float4*)&QS[k + 2][dg * 4];
            float4 q3 = *(float4*)&QS[k + 3][dg * 4];
            #pragma unroll
            for (int j = 0; j < 4; ++j) {
                float4 p = *(float4*)&PIs[rg * 4 + j][k];
                acc[j].x += p.x * q0.x + p.y * q1.x + p.z * q2.x + p.w * q3.x;
                acc[j].y += p.x * q0.y + p.y * q1.y + p.z * q2.y + p.w * q3.y;
                acc[j].z += p.x * q0.z + p.y * q1.z + p.z * q2.z + p.w * q3.z;
                acc[j].w += p.x * q0.w + p.y * q1.w + p.z * q2.w + p.w * q3.w;
            }
        }
    }
    __syncthreads();
    float* mrg = &QS[0][0];
    if (half == 1) {
        #pragma unroll
        for (int j = 0; j < 4; ++j)
            *(float4*)&mrg[tid * 16 + j * 4] = acc[j];
    }
    __syncthreads();
    if (half == 0) {
        #pragma unroll
        for (int j = 0; j < 4; ++j) {
            float4 o = *(const float4*)&mrg[tid * 16 + j * 4];
            o.x = (acc[j].x + o.x) * 8192.f;
            o.y = (acc[j].y + o.y) * 8192.f;
            o.z = (acc[j].z + o.z) * 8192.f;
            o.w = (acc[j].w + o.w) * 8192.f;
            *(float4*)&mapped[(size_t)(r0 + rg * 4 + j) * DD + dg * 4] = o;
        }
    }
}

// ---- fallback (tiny ws): separate pi / mapped --------------------------------
__global__ __launch_bounds__(256) void k_pi(float* __restrict__ Mr,
                                            const float* __restrict__ u,
                                            const float* __restrict__ v) {
    const float4* v4 = (const float4*)v;
    for (int i = blockIdx.x * 256 + threadIdx.x; i < NN * MMX / 4; i += 2048 * 256) {
        int n = i >> 11;
        int m4 = i & 2047;
        float un = u[n];
        float4 vv = v4[m4];
        float4* p = (float4*)Mr + i;
        float4 w = *p;
        w.x = __expf(w.x + un + vv.x);
        w.y = __expf(w.y + un + vv.y);
        w.z = __expf(w.z + un + vv.z);
        w.w = __expf(w.w + un + vv.w);
        *p = w;
    }
}

__global__ __launch_bounds__(256) void k_mapped(const float* __restrict__ pi,
                                                const float* __restrict__ XQ,
                                                float* __restrict__ mapped) {
    __shared__ float XQs[64][128];
    __shared__ float PIs[32][64];
    int r0 = blockIdx.x * 32;
    int t = threadIdx.x;
    int dg = (t & 31) * 4;
    int rg = (t >> 5) * 4;
    float4 acc[4];
    #pragma unroll
    for (int j = 0; j < 4; ++j) acc[j] = make_float4(0.f, 0.f, 0.f, 0.f);

    for (int mb = 0; mb < MMX; mb += 64) {
        __syncthreads();
        #pragma unroll
        for (int i = 0; i < 8; ++i) {
            int f = i * 256 + t;
            int rr = f >> 5;
            int k4 = (f & 31) * 4;
            *(float4*)&XQs[rr][k4] = *(const float4*)&XQ[(size_t)(mb + rr) * DD + k4];
        }
        #pragma unroll
        for (int i = 0; i < 2; ++i) {
            int f = i * 256 + t;
            int rr = f >> 4;
            int c4 = (f & 15) * 4;
            *(float4*)&PIs[rr][c4] = *(const float4*)&pi[(size_t)(r0 + rr) * MMX + mb + c4];
        }
        __syncthreads();
        for (int mm = 0; mm < 64; mm += 4) {
            float4 q0 = *(float4*)&XQs[mm + 0][dg];
            float4 q1 = *(float4*)&XQs[mm + 1][dg];
            float4 q2 = *(float4*)&XQs[mm + 2][dg];
            float4 q3 = *(float4*)&XQs[mm + 3][dg];
            #pragma unroll
            for (int j = 0; j < 4; ++j) {
                float4 p = *(float4*)&PIs[rg + j][mm];
                acc[j].x += p.x * q0.x + p.y * q1.x + p.z * q2.x + p.w * q3.x;
                acc[j].y += p.x * q0.y + p.y * q1.y + p.z * q2.y + p.w * q3.y;
                acc[j].z += p.x * q0.z + p.y * q1.z + p.z * q2.z + p.w * q3.z;
                acc[j].w += p.x * q0.w + p.y * q1.w + p.z * q2.w + p.w * q3.w;
            }
        }
    }
    #pragma unroll
    for (int j = 0; j < 4; ++j) {
        float4 o = acc[j];
        o.x *= 8192.f; o.y *= 8192.f; o.z *= 8192.f; o.w *= 8192.f;
        *(float4*)&mapped[(size_t)(r0 + rg + j) * DD + dg] = o;
    }
}

extern "C" void kernel_launch(void* const* d_in, const int* in_sizes, int n_in,
                              void* d_out, int out_size, void* d_ws, size_t ws_size,
                              hipStream_t stream) {
    const float* XP = (const float*)d_in[0];
    const float* XQ = (const float*)d_in[1];
    float* out = (float*)d_out;
    float* Mr = out + (size_t)NN * DD;            // pi region: Mr / Mrq / pi

    bool big = (ws_size >= 2228224);              // XQT(2 MiB) + u/v/xx/yy
    bool mid = (ws_size >= 131072);
    unsigned* XQT32 = big ? (unsigned*)d_ws : nullptr;
    float* wsf = big ? (float*)((char*)d_ws + 2097152) : (float*)d_ws;
    float* u  = mid ? wsf           : out;
    float* v  = mid ? wsf + 8192    : out + 8192;
    float* xx = mid ? wsf + 16384   : out + 40960;
    float* yy = mid ? wsf + 24576   : out + 49152;
    float* part_big = out;                        // 128 x 8192 (4 MiB, mapped region)
    float* part_mid = out + 65536;                // 64 x 8192 (fallback layout)

    k_init<<<8, 1024, 0, stream>>>(u, v);
    k_sqnorm<<<NN + MMX, 64, 0, stream>>>(XP, XQ, xx, yy);
    if (big) {
        k_gemm_mr_mfma<<<dim3(64, 64), 256, 0, stream>>>(XP, XQ, xx, yy, Mr);
        k_xqt<<<256, 256, 0, stream>>>(XQ, XQT32);
        k_quant<<<8192, 256, 0, stream>>>(Mr);
    } else {
        k_gemm_mr<<<dim3(64, 64), 256, 0, stream>>>(XP, XQ, xx, yy, Mr);
    }

    for (int it = 0; it < NITER; ++it) {
        if (big) {
            k_colpass_q64<<<dim3(8, 128), 256, 0, stream>>>(Mr, u, part_big);
            k_colcombine128<<<64, 256, 0, stream>>>(part_big, v);
            k_rowpass_q<<<1024, 256, 0, stream>>>(Mr, v, u);
        } else {
            k_colpass<<<dim3(8, 64), 256, 0, stream>>>(Mr, u, part_mid);
            k_colcombine<<<32, 256, 0, stream>>>(part_mid, v);
            k_rowpass<<<1024, 256, 0, stream>>>(Mr, v, u);
        }
    }

    if (big) {
        k_pi_mapped_mfma_q<<<512, 256, 0, stream>>>(Mr, XQT32, u, v, out);
    } else if (mid) {
        k_pi_mapped<<<256, 512, 0, stream>>>(Mr, XQ, u, v, out);
    } else {
        k_pi<<<2048, 256, 0, stream>>>(Mr, u, v);
        k_mapped<<<256, 256, 0, stream>>>(Mr, XQ, out);
    }
}

// Round 11
// 3965.430 us; speedup vs baseline: 1.2226x; 1.2226x over previous
//
#include <hip/hip_runtime.h>

// Sinkhorn-log barycentric mapping, N=M=8192, D=128, reg=0.05, 50 iters.
// d_out layout: [ mapped: N*D f32 | pi: N*M f32 ].
// Big-ws path: Mr built by split-bf16 MFMA GEMM, quantized IN PLACE to
// per-row affine int16 (codes at bytes [0,16384) of each 32 KB row slot,
// (base,step) at byte 16384). 100 iteration passes read int16 (134 MB,
// L3-resident), nat-domain online LSE (round-7 proven config, verbatim).
// part (128x8192) in mapped region (out+0), dead before mapped written.
// u,v,xx,yy + bf16 XQT in d_ws. Final fused kernel (512 blk x 256 thr,
// round-8 proven) expands pi=exp(dec+u+v) in DECREASING column order and
// computes mapped = 8192*pi@XQ via bf16 MFMA.

#define NN 8192
#define MMX 8192
#define DD 128
#define NITER 50
#define LOGAB (-9.0109133472792881f)   /* log(1/8192) */
#define NEG20 (-20.0f)                 /* -1/reg */

typedef short bf16x8 __attribute__((ext_vector_type(8)));
typedef float f32x4 __attribute__((ext_vector_type(4)));
typedef unsigned short ushort_t;

static __device__ __forceinline__ void lse_acc(float& m, float& s, float x) {
    float mn = fmaxf(m, x);
    s = s * __expf(m - mn) + __expf(x - mn);
    m = mn;
}
static __device__ __forceinline__ void lse_merge(float& m, float& s, float m2, float s2) {
    float mn = fmaxf(m, m2);
    s = s * __expf(m - mn) + s2 * __expf(m2 - mn);
    m = mn;
}
static __device__ __forceinline__ void lse_acc4(float4& m, float4& s, float4 x) {
    lse_acc(m.x, s.x, x.x);
    lse_acc(m.y, s.y, x.y);
    lse_acc(m.z, s.z, x.z);
    lse_acc(m.w, s.w, x.w);
}
static __device__ __forceinline__ int swz(int r, int k) {
    return k ^ (((r >> 3) & 7) << 2);
}
static __device__ __forceinline__ unsigned f2bf(float x) {
    unsigned u = __float_as_uint(x);
    return (u + 0x7FFF + ((u >> 16) & 1)) >> 16;   // RNE
}
static __device__ __forceinline__ float4 dec4(uint2 w, float stp, float bas) {
    float4 o;
    o.x = (float)(w.x & 0xFFFFu) * stp + bas;
    o.y = (float)(w.x >> 16)     * stp + bas;
    o.z = (float)(w.y & 0xFFFFu) * stp + bas;
    o.w = (float)(w.y >> 16)     * stp + bas;
    return o;
}
// split f32x4 -> hi bf16x4 + lo bf16x4 (packed)
static __device__ __forceinline__ uint2 packhl(float4 x, uint2& lo) {
    unsigned h0 = f2bf(x.x), h1 = f2bf(x.y), h2 = f2bf(x.z), h3 = f2bf(x.w);
    float r0 = x.x - __uint_as_float(h0 << 16);
    float r1 = x.y - __uint_as_float(h1 << 16);
    float r2 = x.z - __uint_as_float(h2 << 16);
    float r3 = x.w - __uint_as_float(h3 << 16);
    lo = make_uint2(f2bf(r0) | (f2bf(r1) << 16), f2bf(r2) | (f2bf(r3) << 16));
    return make_uint2(h0 | (h1 << 16), h2 | (h3 << 16));
}

// ---- zero u, v --------------------------------------------------------------
__global__ void k_init(float* u, float* v) {
    int i = blockIdx.x * 1024 + threadIdx.x;
    if (i < 8192) { u[i] = 0.0f; v[i] = 0.0f; }
}

// ---- squared norms ----------------------------------------------------------
__global__ __launch_bounds__(64) void k_sqnorm(const float* __restrict__ XP,
                                               const float* __restrict__ XQ,
                                               float* __restrict__ xx,
                                               float* __restrict__ yy) {
    int row = blockIdx.x;
    int lane = threadIdx.x;
    const float* src = (row < NN) ? (XP + (size_t)row * DD)
                                  : (XQ + (size_t)(row - NN) * DD);
    float2 w = *(const float2*)&src[lane * 2];
    float sres = w.x * w.x + w.y * w.y;
    #pragma unroll
    for (int off = 32; off > 0; off >>= 1)
        sres += __shfl_down(sres, off, 64);
    if (lane == 0) {
        if (row < NN) xx[row] = sres;
        else          yy[row - NN] = sres;
    }
}

// ---- XQT[d][m] = bf16(XQ[m][d]) ---------------------------------------------
__global__ __launch_bounds__(256) void k_xqt(const float* __restrict__ XQ,
                                             unsigned* __restrict__ XQT32) {
    __shared__ float As[32][129];
    int mb = blockIdx.x * 32;
    int t = threadIdx.x;
    int r = t >> 3, c0 = (t & 7) * 16;
    #pragma unroll
    for (int j = 0; j < 4; ++j)
        *(float4*)&As[r][c0 + j * 4] = *(const float4*)&XQ[(size_t)(mb + r) * DD + c0 + j * 4];
    __syncthreads();
    int d = t >> 1, p0 = (t & 1) * 8;
    #pragma unroll
    for (int j = 0; j < 8; ++j) {
        int pp = p0 + j;
        unsigned lo = f2bf(As[2 * pp][d]);
        unsigned hi = f2bf(As[2 * pp + 1][d]);
        XQT32[(size_t)d * 4096 + (mb >> 1) + pp] = lo | (hi << 16);
    }
}

// ---- MFMA Mr GEMM: Mr = -20*max(0, xx+yy-2*(hh+hl+lh)) ----------------------
__global__ __launch_bounds__(256, 2) void k_gemm_mr_mfma(const float* __restrict__ XP,
                                                         const float* __restrict__ XQ,
                                                         const float* __restrict__ xx,
                                                         const float* __restrict__ yy,
                                                         float* __restrict__ Mr) {
    __shared__ ushort_t Ah[128 * 64], Al[128 * 64];
    __shared__ ushort_t Bh[128 * 64], Bl[128 * 64];
    int rb = blockIdx.y * 128, cb = blockIdx.x * 128;
    int t = threadIdx.x;
    int w = t >> 6, lane = t & 63;
    int lane15 = lane & 15, lhi = lane >> 4;
    int wr = (w >> 1) * 64, wc = (w & 1) * 64;

    f32x4 acc00 = (f32x4)(0.f), acc01 = acc00, acc02 = acc00, acc03 = acc00;
    f32x4 acc10 = acc00, acc11 = acc00, acc12 = acc00, acc13 = acc00;
    f32x4 acc20 = acc00, acc21 = acc00, acc22 = acc00, acc23 = acc00;
    f32x4 acc30 = acc00, acc31 = acc00, acc32 = acc00, acc33 = acc00;

    for (int kc = 0; kc < 128; kc += 64) {
        __syncthreads();
        #pragma unroll
        for (int i = 0; i < 8; ++i) {
            int f = i * 256 + t;
            int r = f >> 4;
            int k4 = (f & 15) * 4;
            int g = k4 >> 3, hf = (k4 >> 2) & 1;
            int wa = r * 64 + ((g ^ (r & 7)) * 8 + hf * 4);
            float4 a = *(const float4*)&XP[(size_t)(rb + r) * DD + kc + k4];
            float4 b = *(const float4*)&XQ[(size_t)(cb + r) * DD + kc + k4];
            uint2 alo, blo;
            uint2 ahi = packhl(a, alo);
            uint2 bhi = packhl(b, blo);
            *(uint2*)&Ah[wa] = ahi; *(uint2*)&Al[wa] = alo;
            *(uint2*)&Bh[wa] = bhi; *(uint2*)&Bl[wa] = blo;
        }
        __syncthreads();
        #pragma unroll
        for (int ks = 0; ks < 2; ++ks) {
            int g = ks * 4 + lhi;
            bf16x8 ah[4], al[4], bh[4], bl[4];
            #pragma unroll
            for (int i = 0; i < 4; ++i) {
                int ar = wr + i * 16 + lane15;
                int ao = ar * 64 + ((g ^ (ar & 7)) * 8);
                ah[i] = *(bf16x8*)&Ah[ao];
                al[i] = *(bf16x8*)&Al[ao];
                int br = wc + i * 16 + lane15;
                int bo = br * 64 + ((g ^ (br & 7)) * 8);
                bh[i] = *(bf16x8*)&Bh[bo];
                bl[i] = *(bf16x8*)&Bl[bo];
            }
            #define MM3(AC, I, J) \
                AC = __builtin_amdgcn_mfma_f32_16x16x32_bf16(ah[I], bh[J], AC, 0, 0, 0); \
                AC = __builtin_amdgcn_mfma_f32_16x16x32_bf16(ah[I], bl[J], AC, 0, 0, 0); \
                AC = __builtin_amdgcn_mfma_f32_16x16x32_bf16(al[I], bh[J], AC, 0, 0, 0);
            MM3(acc00,0,0) MM3(acc01,0,1) MM3(acc02,0,2) MM3(acc03,0,3)
            MM3(acc10,1,0) MM3(acc11,1,1) MM3(acc12,1,2) MM3(acc13,1,3)
            MM3(acc20,2,0) MM3(acc21,2,1) MM3(acc22,2,2) MM3(acc23,2,3)
            MM3(acc30,3,0) MM3(acc31,3,1) MM3(acc32,3,2) MM3(acc33,3,3)
            #undef MM3
        }
    }
    float yv[4];
    #pragma unroll
    for (int j = 0; j < 4; ++j) yv[j] = yy[cb + wc + j * 16 + lane15];
    #define EPI(AC, I, J) { \
        _Pragma("unroll") \
        for (int reg = 0; reg < 4; ++reg) { \
            int gr = rb + wr + I * 16 + lhi * 4 + reg; \
            float C = xx[gr] + yv[J] - 2.f * AC[reg]; \
            Mr[(size_t)gr * MMX + cb + wc + J * 16 + lane15] = NEG20 * fmaxf(C, 0.f); \
        } }
    EPI(acc00,0,0) EPI(acc01,0,1) EPI(acc02,0,2) EPI(acc03,0,3)
    EPI(acc10,1,0) EPI(acc11,1,1) EPI(acc12,1,2) EPI(acc13,1,3)
    EPI(acc20,2,0) EPI(acc21,2,1) EPI(acc22,2,2) EPI(acc23,2,3)
    EPI(acc30,3,0) EPI(acc31,3,1) EPI(acc32,3,2) EPI(acc33,3,3)
    #undef EPI
}

// ---- f32 vector Mr GEMM (fallback paths only) --------------------------------
__global__ __launch_bounds__(256) void k_gemm_mr(const float* __restrict__ XP,
                                                 const float* __restrict__ XQ,
                                                 const float* __restrict__ xx,
                                                 const float* __restrict__ yy,
                                                 float* __restrict__ Mr) {
    __shared__ float As[128][64];
    __shared__ float Bs[128][64];
    int rb = blockIdx.y * 128, cb = blockIdx.x * 128;
    int t = threadIdx.x;
    int ty = t >> 4, tx = t & 15;
    int r0 = ty * 8, c0 = tx * 8;
    float acc[8][8] = {};

    for (int kc = 0; kc < 128; kc += 64) {
        __syncthreads();
        #pragma unroll
        for (int i = 0; i < 8; ++i) {
            int f = i * 256 + t;
            int r = f >> 4;
            int k4 = (f & 15) * 4;
            *(float4*)&As[r][swz(r, k4)] = *(const float4*)&XP[(size_t)(rb + r) * DD + kc + k4];
            *(float4*)&Bs[r][swz(r, k4)] = *(const float4*)&XQ[(size_t)(cb + r) * DD + kc + k4];
        }
        __syncthreads();
        for (int k = 0; k < 64; k += 4) {
            float4 a[8], b[8];
            #pragma unroll
            for (int i = 0; i < 8; ++i) {
                a[i] = *(float4*)&As[r0 + i][swz(r0 + i, k)];
                b[i] = *(float4*)&Bs[c0 + i][swz(c0 + i, k)];
            }
            #pragma unroll
            for (int i = 0; i < 8; ++i)
                #pragma unroll
                for (int j = 0; j < 8; ++j)
                    acc[i][j] += a[i].x * b[j].x + a[i].y * b[j].y +
                                 a[i].z * b[j].z + a[i].w * b[j].w;
        }
    }

    float yv[8];
    *(float4*)&yv[0] = *(const float4*)&yy[cb + c0];
    *(float4*)&yv[4] = *(const float4*)&yy[cb + c0 + 4];
    #pragma unroll
    for (int i = 0; i < 8; ++i) {
        int gr = rb + r0 + i;
        float xxi = xx[gr];
        float4 o0, o1;
        o0.x = NEG20 * fmaxf(xxi + yv[0] - 2.f * acc[i][0], 0.f);
        o0.y = NEG20 * fmaxf(xxi + yv[1] - 2.f * acc[i][1], 0.f);
        o0.z = NEG20 * fmaxf(xxi + yv[2] - 2.f * acc[i][2], 0.f);
        o0.w = NEG20 * fmaxf(xxi + yv[3] - 2.f * acc[i][3], 0.f);
        o1.x = NEG20 * fmaxf(xxi + yv[4] - 2.f * acc[i][4], 0.f);
        o1.y = NEG20 * fmaxf(xxi + yv[5] - 2.f * acc[i][5], 0.f);
        o1.z = NEG20 * fmaxf(xxi + yv[6] - 2.f * acc[i][6], 0.f);
        o1.w = NEG20 * fmaxf(xxi + yv[7] - 2.f * acc[i][7], 0.f);
        *(float4*)&Mr[(size_t)gr * MMX + cb + c0] = o0;
        *(float4*)&Mr[(size_t)gr * MMX + cb + c0 + 4] = o1;
    }
}

// ---- quantize Mr row -> in-slot int16 + (base,step) --------------------------
__global__ __launch_bounds__(256) void k_quant(float* __restrict__ Mr) {
    float* slot = Mr + (size_t)blockIdx.x * MMX;
    int t = threadIdx.x;
    float4 x[8];
    float mn = 1e30f, mx = -1e30f;
    #pragma unroll
    for (int i = 0; i < 8; ++i) {
        x[i] = *(const float4*)&slot[(t + 256 * i) * 4];
        mn = fminf(mn, fminf(fminf(x[i].x, x[i].y), fminf(x[i].z, x[i].w)));
        mx = fmaxf(mx, fmaxf(fmaxf(x[i].x, x[i].y), fmaxf(x[i].z, x[i].w)));
    }
    #pragma unroll
    for (int off = 32; off > 0; off >>= 1) {
        mn = fminf(mn, __shfl_xor(mn, off));
        mx = fmaxf(mx, __shfl_xor(mx, off));
    }
    __shared__ float smn[4], smx[4];
    int wid = t >> 6;
    if ((t & 63) == 0) { smn[wid] = mn; smx[wid] = mx; }
    __syncthreads();
    mn = fminf(fminf(smn[0], smn[1]), fminf(smn[2], smn[3]));
    mx = fmaxf(fmaxf(smx[0], smx[1]), fmaxf(smx[2], smx[3]));
    float span = fmaxf(mx - mn, 1e-20f);
    float inv = 65535.0f / span;
    float stp = span * (1.0f / 65535.0f);
    uint2* out16 = (uint2*)slot;
    #pragma unroll
    for (int i = 0; i < 8; ++i) {
        unsigned q0 = (unsigned)fminf(rintf((x[i].x - mn) * inv), 65535.f);
        unsigned q1 = (unsigned)fminf(rintf((x[i].y - mn) * inv), 65535.f);
        unsigned q2 = (unsigned)fminf(rintf((x[i].z - mn) * inv), 65535.f);
        unsigned q3 = (unsigned)fminf(rintf((x[i].w - mn) * inv), 65535.f);
        out16[t + 256 * i] = make_uint2(q0 | (q1 << 16), q2 | (q3 << 16));
    }
    if (t == 0) *(float2*)&slot[4096] = make_float2(mn, stp);
}

// ---- column-LSE partial (round-7 verbatim): (8,128) grid, 1024c x 64r --------
__global__ __launch_bounds__(256) void k_colpass_q64(const float* __restrict__ Mr,
                                                     const float* __restrict__ u,
                                                     float* __restrict__ part) {
    int c = blockIdx.x * 1024 + threadIdx.x * 4;
    int n0 = blockIdx.y * 64;
    float4 mx = make_float4(-1e30f, -1e30f, -1e30f, -1e30f);
    float4 s = make_float4(0.f, 0.f, 0.f, 0.f);
    #pragma unroll 8
    for (int r = 0; r < 64; ++r) {
        const float* slot = Mr + (size_t)(n0 + r) * MMX;
        float2 bs = *(const float2*)&slot[4096];
        float basu = bs.x + u[n0 + r];
        uint2 w = *(const uint2*)((const ushort_t*)slot + c);
        lse_acc4(mx, s, dec4(w, bs.y, basu));
    }
    float4 o;
    o.x = mx.x + __logf(s.x);
    o.y = mx.y + __logf(s.y);
    o.z = mx.z + __logf(s.z);
    o.w = mx.w + __logf(s.w);
    *(float4*)&part[(size_t)blockIdx.y * MMX + c] = o;
}

// ---- combine 128 chunk-LSEs -> v[m], 2-way split chain -----------------------
__global__ __launch_bounds__(256) void k_colcombine128(const float* __restrict__ part,
                                                       float* __restrict__ v) {
    int t = threadIdx.x;
    int col = blockIdx.x * 128 + (t & 127);
    int half = t >> 7;
    float mx = -1e30f, s = 0.f;
    #pragma unroll 8
    for (int ch = 0; ch < 64; ++ch)
        lse_acc(mx, s, part[(size_t)(half * 64 + ch) * MMX + col]);
    __shared__ float sm[256];
    if (half) { sm[t & 127] = mx; sm[128 + (t & 127)] = s; }
    __syncthreads();
    if (!half) {
        lse_merge(mx, s, sm[t], sm[128 + t]);
        v[col] = LOGAB - (mx + __logf(s));
    }
}

// ---- row-LSE (round-7 verbatim): 1024 blocks x 8 rows ------------------------
__global__ __launch_bounds__(256) void k_rowpass_q(const float* __restrict__ Mr,
                                                   const float* __restrict__ v,
                                                   float* __restrict__ u) {
    int n0 = blockIdx.x * 8;
    int t = threadIdx.x;
    float basr[8], stpr[8];
    const ushort_t* us[8];
    #pragma unroll
    for (int r = 0; r < 8; ++r) {
        const float* slot = Mr + (size_t)(n0 + r) * MMX;
        float2 bs = *(const float2*)&slot[4096];
        basr[r] = bs.x;
        stpr[r] = bs.y;
        us[r] = (const ushort_t*)slot;
    }
    float4 mx[8], s[8];
    #pragma unroll
    for (int r = 0; r < 8; ++r) {
        mx[r] = make_float4(-1e30f, -1e30f, -1e30f, -1e30f);
        s[r] = make_float4(0.f, 0.f, 0.f, 0.f);
    }
    const float4* v4 = (const float4*)v;
    for (int i = t; i < MMX / 4; i += 256) {
        float4 vv = v4[i];
        #pragma unroll
        for (int r = 0; r < 8; ++r) {
            uint2 w = *(const uint2*)&us[r][i * 4];
            float4 d = dec4(w, stpr[r], basr[r]);
            d.x += vv.x; d.y += vv.y; d.z += vv.z; d.w += vv.w;
            lse_acc4(mx[r], s[r], d);
        }
    }
    __shared__ float smm[8][4], sss[8][4];
    int wid = t >> 6, lane = t & 63;
    #pragma unroll
    for (int r = 0; r < 8; ++r) {
        float m1 = mx[r].x, s1 = s[r].x;
        lse_merge(m1, s1, mx[r].y, s[r].y);
        lse_merge(m1, s1, mx[r].z, s[r].z);
        lse_merge(m1, s1, mx[r].w, s[r].w);
        #pragma unroll
        for (int off = 32; off > 0; off >>= 1) {
            float m2 = __shfl_xor(m1, off);
            float s2 = __shfl_xor(s1, off);
            lse_merge(m1, s1, m2, s2);
        }
        if (lane == 0) { smm[r][wid] = m1; sss[r][wid] = s1; }
    }
    __syncthreads();
    if (t < 8) {
        float m1 = smm[t][0], s1 = sss[t][0];
        lse_merge(m1, s1, smm[t][1], sss[t][1]);
        lse_merge(m1, s1, smm[t][2], sss[t][2]);
        lse_merge(m1, s1, smm[t][3], sss[t][3]);
        u[n0 + t] = LOGAB - (m1 + __logf(s1));
    }
}

// ---- f32 colpass/combine/rowpass (fallback paths) ----------------------------
__global__ __launch_bounds__(256) void k_colpass(const float* __restrict__ Mr,
                                                 const float* __restrict__ u,
                                                 float* __restrict__ part) {
    int c = blockIdx.x * 1024 + threadIdx.x * 4;
    int n0 = blockIdx.y * 128;
    float4 mx = make_float4(-1e30f, -1e30f, -1e30f, -1e30f);
    float4 s = make_float4(0.f, 0.f, 0.f, 0.f);
    #pragma unroll 8
    for (int r = 0; r < 128; ++r) {
        float un = u[n0 + r];
        float4 w = *(const float4*)&Mr[(size_t)(n0 + r) * MMX + c];
        w.x += un; w.y += un; w.z += un; w.w += un;
        lse_acc4(mx, s, w);
    }
    float4 o;
    o.x = mx.x + __logf(s.x);
    o.y = mx.y + __logf(s.y);
    o.z = mx.z + __logf(s.z);
    o.w = mx.w + __logf(s.w);
    *(float4*)&part[(size_t)blockIdx.y * MMX + c] = o;
}

__global__ __launch_bounds__(256) void k_colcombine(const float* __restrict__ part,
                                                    float* __restrict__ v) {
    int m = blockIdx.x * 256 + threadIdx.x;
    float mx = -1e30f, s = 0.f;
    #pragma unroll 8
    for (int ch = 0; ch < 64; ++ch)
        lse_acc(mx, s, part[(size_t)ch * MMX + m]);
    v[m] = LOGAB - (mx + __logf(s));
}

__global__ __launch_bounds__(256) void k_rowpass(const float* __restrict__ Mr,
                                                 const float* __restrict__ v,
                                                 float* __restrict__ u) {
    int n0 = blockIdx.x * 8;
    int t = threadIdx.x;
    float4 mx[8], s[8];
    #pragma unroll
    for (int r = 0; r < 8; ++r) {
        mx[r] = make_float4(-1e30f, -1e30f, -1e30f, -1e30f);
        s[r] = make_float4(0.f, 0.f, 0.f, 0.f);
    }
    const float4* v4 = (const float4*)v;
    for (int i = t; i < MMX / 4; i += 256) {
        float4 vv = v4[i];
        #pragma unroll
        for (int r = 0; r < 8; ++r) {
            float4 w = *(const float4*)&Mr[(size_t)(n0 + r) * MMX + i * 4];
            w.x += vv.x; w.y += vv.y; w.z += vv.z; w.w += vv.w;
            lse_acc4(mx[r], s[r], w);
        }
    }
    __shared__ float smm[8][4], sss[8][4];
    int wid = t >> 6, lane = t & 63;
    #pragma unroll
    for (int r = 0; r < 8; ++r) {
        float m1 = mx[r].x, s1 = s[r].x;
        lse_merge(m1, s1, mx[r].y, s[r].y);
        lse_merge(m1, s1, mx[r].z, s[r].z);
        lse_merge(m1, s1, mx[r].w, s[r].w);
        #pragma unroll
        for (int off = 32; off > 0; off >>= 1) {
            float m2 = __shfl_xor(m1, off);
            float s2 = __shfl_xor(s1, off);
            lse_merge(m1, s1, m2, s2);
        }
        if (lane == 0) { smm[r][wid] = m1; sss[r][wid] = s1; }
    }
    __syncthreads();
    if (t < 8) {
        float m1 = smm[t][0], s1 = sss[t][0];
        lse_merge(m1, s1, smm[t][1], sss[t][1]);
        lse_merge(m1, s1, smm[t][2], sss[t][2]);
        lse_merge(m1, s1, smm[t][3], sss[t][3]);
        u[n0 + t] = LOGAB - (m1 + __logf(s1));
    }
}

// ---- MFMA FUSED (round-8 proven): 512 blk x 256 thr x 16 rows ----------------
__global__ __launch_bounds__(256) void k_pi_mapped_mfma_q(float* __restrict__ P,
                                                          const unsigned* __restrict__ XQT32,
                                                          const float* __restrict__ u,
                                                          const float* __restrict__ v,
                                                          float* __restrict__ mapped) {
    __shared__ unsigned short PIs[16 * 64];
    __shared__ unsigned short QTs[128 * 64];
    int r0 = blockIdx.x * 16;
    int t = threadIdx.x;                 // 0..255
    int wid = t >> 6, lane = t & 63;
    int lane15 = lane & 15, lhi = lane >> 4;
    int dbase = wid * 32;
    int prow = t >> 4;
    int pm4 = (t & 15) * 4;
    int pgran = (t & 15) >> 1, phalf = t & 1;
    int qd = t >> 1;
    int qg0 = (t & 1) * 4;

    float* slotp = P + (size_t)(r0 + prow) * MMX;
    const ushort_t* usp = (const ushort_t*)slotp;
    float2 bs = *(const float2*)&slotp[4096];
    float stp = bs.y;
    float basu = bs.x + u[r0 + prow];

    f32x4 acc[2];
    acc[0] = (f32x4)(0.f);
    acc[1] = (f32x4)(0.f);

    int mb0 = MMX - 64;
    uint2 pq = *(const uint2*)&usp[mb0 + pm4];
    float4 vv = *(const float4*)&v[mb0 + pm4];
    uint4 xq0 = *(const uint4*)&XQT32[(size_t)qd * 4096 + (mb0 >> 1) + qg0 * 4];
    uint4 xq1 = *(const uint4*)&XQT32[(size_t)qd * 4096 + (mb0 >> 1) + qg0 * 4 + 4];
    uint4 xq2 = *(const uint4*)&XQT32[(size_t)qd * 4096 + (mb0 >> 1) + qg0 * 4 + 8];
    uint4 xq3 = *(const uint4*)&XQT32[(size_t)qd * 4096 + (mb0 >> 1) + qg0 * 4 + 12];

    for (int mb = mb0; mb >= 0; mb -= 64) {
        __syncthreads();
        float4 d = dec4(pq, stp, basu);
        float4 w;
        w.x = __expf(d.x + vv.x);
        w.y = __expf(d.y + vv.y);
        w.z = __expf(d.z + vv.z);
        w.w = __expf(d.w + vv.w);
        uint2 pk;
        pk.x = f2bf(w.x) | (f2bf(w.y) << 16);
        pk.y = f2bf(w.z) | (f2bf(w.w) << 16);
        *(uint2*)&PIs[prow * 64 + (pgran ^ (prow & 7)) * 8 + phalf * 4] = pk;
        *(uint4*)&QTs[qd * 64 + ((qg0 + 0) ^ (qd & 7)) * 8] = xq0;
        *(uint4*)&QTs[qd * 64 + ((qg0 + 1) ^ (qd & 7)) * 8] = xq1;
        *(uint4*)&QTs[qd * 64 + ((qg0 + 2) ^ (qd & 7)) * 8] = xq2;
        *(uint4*)&QTs[qd * 64 + ((qg0 + 3) ^ (qd & 7)) * 8] = xq3;
        __syncthreads();
        *(float4*)&slotp[mb + pm4] = w;
        if (mb > 0) {
            int nb = mb - 64;
            pq = *(const uint2*)&usp[nb + pm4];
            vv = *(const float4*)&v[nb + pm4];
            xq0 = *(const uint4*)&XQT32[(size_t)qd * 4096 + (nb >> 1) + qg0 * 4];
            xq1 = *(const uint4*)&XQT32[(size_t)qd * 4096 + (nb >> 1) + qg0 * 4 + 4];
            xq2 = *(const uint4*)&XQT32[(size_t)qd * 4096 + (nb >> 1) + qg0 * 4 + 8];
            xq3 = *(const uint4*)&XQT32[(size_t)qd * 4096 + (nb >> 1) + qg0 * 4 + 12];
        }
        bf16x8 afr[2];
        #pragma unroll
        for (int ks = 0; ks < 2; ++ks) {
            int g = ks * 4 + lhi;
            afr[ks] = *(bf16x8*)&PIs[lane15 * 64 + (g ^ (lane15 & 7)) * 8];
        }
        #pragma unroll
        for (int dt = 0; dt < 2; ++dt) {
            int drow = dbase + dt * 16 + lane15;
            #pragma unroll
            for (int ks = 0; ks < 2; ++ks) {
                int g = ks * 4 + lhi;
                bf16x8 bfr = *(bf16x8*)&QTs[drow * 64 + (g ^ (drow & 7)) * 8];
                acc[dt] = __builtin_amdgcn_mfma_f32_16x16x32_bf16(afr[ks], bfr, acc[dt], 0, 0, 0);
            }
        }
    }
    #pragma unroll
    for (int dt = 0; dt < 2; ++dt) {
        int dcol = dbase + dt * 16 + lane15;
        #pragma unroll
        for (int reg = 0; reg < 4; ++reg) {
            int nrow = r0 + lhi * 4 + reg;
            mapped[(size_t)nrow * DD + dcol] = acc[dt][reg] * 8192.f;
        }
    }
}

// ---- vector FUSED (mid-ws path, f32 Mr) --------------------------------------
__global__ __launch_bounds__(512, 1) void k_pi_mapped(float* __restrict__ P,
                                                      const float* __restrict__ XQ,
                                                      const float* __restrict__ u,
                                                      const float* __restrict__ v,
                                                      float* __restrict__ mapped) {
    __shared__ float PIs[32][68];
    __shared__ float QS[64][128];
    int r0 = blockIdx.x * 32;
    int t = threadIdx.x;
    int tid = t & 255;
    int half = t >> 8;
    int rg = tid >> 5;
    int dg = tid & 31;
    int prow = t >> 4;
    int pc4 = (t & 15) * 4;
    int qrb = t >> 5;
    int qc4 = (t & 31) * 4;
    float urow = u[r0 + prow];

    float4 acc[4];
    acc[0] = acc[1] = acc[2] = acc[3] = make_float4(0.f, 0.f, 0.f, 0.f);

    float4 pw, vv, xq0, xq1, xq2, xq3;
    pw = *(const float4*)&P[(size_t)(r0 + prow) * MMX + pc4];
    vv = *(const float4*)&v[pc4];
    xq0 = *(const float4*)&XQ[(size_t)(qrb) * DD + qc4];
    xq1 = *(const float4*)&XQ[(size_t)(16 + qrb) * DD + qc4];
    xq2 = *(const float4*)&XQ[(size_t)(32 + qrb) * DD + qc4];
    xq3 = *(const float4*)&XQ[(size_t)(48 + qrb) * DD + qc4];

    for (int mb = 0; mb < MMX; mb += 64) {
        __syncthreads();
        float4 w;
        w.x = __expf(pw.x + urow + vv.x);
        w.y = __expf(pw.y + urow + vv.y);
        w.z = __expf(pw.z + urow + vv.z);
        w.w = __expf(pw.w + urow + vv.w);
        *(float4*)&PIs[prow][pc4] = w;
        *(float4*)&QS[qrb][qc4] = xq0;
        *(float4*)&QS[16 + qrb][qc4] = xq1;
        *(float4*)&QS[32 + qrb][qc4] = xq2;
        *(float4*)&QS[48 + qrb][qc4] = xq3;
        __syncthreads();
        *(float4*)&P[(size_t)(r0 + prow) * MMX + mb + pc4] = w;
        if (mb + 64 < MMX) {
            int nb = mb + 64;
            pw = *(const float4*)&P[(size_t)(r0 + prow) * MMX + nb + pc4];
            vv = *(const float4*)&v[nb + pc4];
            xq0 = *(const float4*)&XQ[(size_t)(nb + qrb) * DD + qc4];
            xq1 = *(const float4*)&XQ[(size_t)(nb + 16 + qrb) * DD + qc4];
            xq2 = *(const float4*)&XQ[(size_t)(nb + 32 + qrb) * DD + qc4];
            xq3 = *(const float4*)&XQ[(size_t)(nb + 48 + qrb) * DD + qc4];
        }
        #pragma unroll
        for (int sstep = 0; sstep < 8; ++sstep) {
            int k = (half * 8 + sstep) * 4;
            float4 q0 = *(float4*)&QS[k + 0][dg * 4];
            float4 q1 = *(float4*)&QS[k + 1][dg * 4];
            float4 q2 = *(float4*)&QS[k + 2][dg * 4];
            float4 q3 = *(float4*)&QS[k + 3][dg * 4];
            #pragma unroll
            for (int j = 0; j < 4; ++j) {
                float4 p = *(float4*)&PIs[rg * 4 + j][k];
                acc[j].x += p.x * q0.x + p.y * q1.x + p.z * q2.x + p.w * q3.x;
                acc[j].y += p.x * q0.y + p.y * q1.y + p.z * q2.y + p.w * q3.y;
                acc[j].z += p.x * q0.z + p.y * q1.z + p.z * q2.z + p.w * q3.z;
                acc[j].w += p.x * q0.w + p.y * q1.w + p.z * q2.w + p.w * q3.w;
            }
        }
    }
    __syncthreads();
    float* mrg = &QS[0][0];
    if (half == 1) {
        #pragma unroll
        for (int j = 0; j < 4; ++j)
            *(float4*)&mrg[tid * 16 + j * 4] = acc[j];
    }
    __syncthreads();
    if (half == 0) {
        #pragma unroll
        for (int j = 0; j < 4; ++j) {
            float4 o = *(const float4*)&mrg[tid * 16 + j * 4];
            o.x = (acc[j].x + o.x) * 8192.f;
            o.y = (acc[j].y + o.y) * 8192.f;
            o.z = (acc[j].z + o.z) * 8192.f;
            o.w = (acc[j].w + o.w) * 8192.f;
            *(float4*)&mapped[(size_t)(r0 + rg * 4 + j) * DD + dg * 4] = o;
        }
    }
}

// ---- fallback (tiny ws): separate pi / mapped --------------------------------
__global__ __launch_bounds__(256) void k_pi(float* __restrict__ Mr,
                                            const float* __restrict__ u,
                                            const float* __restrict__ v) {
    const float4* v4 = (const float4*)v;
    for (int i = blockIdx.x * 256 + threadIdx.x; i < NN * MMX / 4; i += 2048 * 256) {
        int n = i >> 11;
        int m4 = i & 2047;
        float un = u[n];
        float4 vv = v4[m4];
        float4* p = (float4*)Mr + i;
        float4 w = *p;
        w.x = __expf(w.x + un + vv.x);
        w.y = __expf(w.y + un + vv.y);
        w.z = __expf(w.z + un + vv.z);
        w.w = __expf(w.w + un + vv.w);
        *p = w;
    }
}

__global__ __launch_bounds__(256) void k_mapped(const float* __restrict__ pi,
                                                const float* __restrict__ XQ,
                                                float* __restrict__ mapped) {
    __shared__ float XQs[64][128];
    __shared__ float PIs[32][64];
    int r0 = blockIdx.x * 32;
    int t = threadIdx.x;
    int dg = (t & 31) * 4;
    int rg = (t >> 5) * 4;
    float4 acc[4];
    #pragma unroll
    for (int j = 0; j < 4; ++j) acc[j] = make_float4(0.f, 0.f, 0.f, 0.f);

    for (int mb = 0; mb < MMX; mb += 64) {
        __syncthreads();
        #pragma unroll
        for (int i = 0; i < 8; ++i) {
            int f = i * 256 + t;
            int rr = f >> 5;
            int k4 = (f & 31) * 4;
            *(float4*)&XQs[rr][k4] = *(const float4*)&XQ[(size_t)(mb + rr) * DD + k4];
        }
        #pragma unroll
        for (int i = 0; i < 2; ++i) {
            int f = i * 256 + t;
            int rr = f >> 4;
            int c4 = (f & 15) * 4;
            *(float4*)&PIs[rr][c4] = *(const float4*)&pi[(size_t)(r0 + rr) * MMX + mb + c4];
        }
        __syncthreads();
        for (int mm = 0; mm < 64; mm += 4) {
            float4 q0 = *(float4*)&XQs[mm + 0][dg];
            float4 q1 = *(float4*)&XQs[mm + 1][dg];
            float4 q2 = *(float4*)&XQs[mm + 2][dg];
            float4 q3 = *(float4*)&XQs[mm + 3][dg];
            #pragma unroll
            for (int j = 0; j < 4; ++j) {
                float4 p = *(float4*)&PIs[rg + j][mm];
                acc[j].x += p.x * q0.x + p.y * q1.x + p.z * q2.x + p.w * q3.x;
                acc[j].y += p.x * q0.y + p.y * q1.y + p.z * q2.y + p.w * q3.y;
                acc[j].z += p.x * q0.z + p.y * q1.z + p.z * q2.z + p.w * q3.z;
                acc[j].w += p.x * q0.w + p.y * q1.w + p.z * q2.w + p.w * q3.w;
            }
        }
    }
    #pragma unroll
    for (int j = 0; j < 4; ++j) {
        float4 o = acc[j];
        o.x *= 8192.f; o.y *= 8192.f; o.z *= 8192.f; o.w *= 8192.f;
        *(float4*)&mapped[(size_t)(r0 + rg + j) * DD + dg] = o;
    }
}

extern "C" void kernel_launch(void* const* d_in, const int* in_sizes, int n_in,
                              void* d_out, int out_size, void* d_ws, size_t ws_size,
                              hipStream_t stream) {
    const float* XP = (const float*)d_in[0];
    const float* XQ = (const float*)d_in[1];
    float* out = (float*)d_out;
    float* Mr = out + (size_t)NN * DD;            // pi region: Mr / Mrq / pi

    bool big = (ws_size >= 2228224);              // XQT(2 MiB) + u/v/xx/yy
    bool mid = (ws_size >= 131072);
    unsigned* XQT32 = big ? (unsigned*)d_ws : nullptr;
    float* wsf = big ? (float*)((char*)d_ws + 2097152) : (float*)d_ws;
    float* u  = mid ? wsf           : out;
    float* v  = mid ? wsf + 8192    : out + 8192;
    float* xx = mid ? wsf + 16384   : out + 40960;
    float* yy = mid ? wsf + 24576   : out + 49152;
    float* part_big = out;                        // 128 x 8192 (4 MiB, mapped region)
    float* part_mid = out + 65536;                // 64 x 8192 (fallback layout)

    k_init<<<8, 1024, 0, stream>>>(u, v);
    k_sqnorm<<<NN + MMX, 64, 0, stream>>>(XP, XQ, xx, yy);
    if (big) {
        k_gemm_mr_mfma<<<dim3(64, 64), 256, 0, stream>>>(XP, XQ, xx, yy, Mr);
        k_xqt<<<256, 256, 0, stream>>>(XQ, XQT32);
        k_quant<<<8192, 256, 0, stream>>>(Mr);
    } else {
        k_gemm_mr<<<dim3(64, 64), 256, 0, stream>>>(XP, XQ, xx, yy, Mr);
    }

    for (int it = 0; it < NITER; ++it) {
        if (big) {
            k_colpass_q64<<<dim3(8, 128), 256, 0, stream>>>(Mr, u, part_big);
            k_colcombine128<<<64, 256, 0, stream>>>(part_big, v);
            k_rowpass_q<<<1024, 256, 0, stream>>>(Mr, v, u);
        } else {
            k_colpass<<<dim3(8, 64), 256, 0, stream>>>(Mr, u, part_mid);
            k_colcombine<<<32, 256, 0, stream>>>(part_mid, v);
            k_rowpass<<<1024, 256, 0, stream>>>(Mr, v, u);
        }
    }

    if (big) {
        k_pi_mapped_mfma_q<<<512, 256, 0, stream>>>(Mr, XQT32, u, v, out);
    } else if (mid) {
        k_pi_mapped<<<256, 512, 0, stream>>>(Mr, XQ, u, v, out);
    } else {
        k_pi<<<2048, 256, 0, stream>>>(Mr, u, v);
        k_mapped<<<256, 256, 0, stream>>>(Mr, XQ, out);
    }
}

// Round 12
// 3701.980 us; speedup vs baseline: 1.3097x; 1.0712x over previous
//
#include <hip/hip_runtime.h>

// Sinkhorn-log barycentric mapping, N=M=8192, D=128, reg=0.05, 50 iters.
// d_out layout: [ mapped: N*D f32 | pi: N*M f32 ].
// Big-ws path: Mr built by split-bf16 MFMA GEMM, quantized IN PLACE to
// per-row affine int16 (codes at bytes [0,16384) of each 32 KB row slot,
// (base,step) at byte 16384). 100 iteration passes read int16 (134 MB,
// L3-resident) with a SINGLE-__expf branchless online LSE (nat domain —
// round-9's exp2f went through OCML; __expf inlines to v_exp_f32).
// part (128x8192) in mapped region (out+0), dead before mapped written.
// u,v,xx,yy + bf16 XQT in d_ws. Final fused kernel (512 blk x 256 thr)
// expands pi=exp(dec+u+v) in DECREASING column order; mapped=8192*pi@XQ
// via bf16 MFMA.

#define NN 8192
#define MMX 8192
#define DD 128
#define NITER 50
#define LOGAB (-9.0109133472792881f)   /* log(1/8192) */
#define NEG20 (-20.0f)                 /* -1/reg */

typedef short bf16x8 __attribute__((ext_vector_type(8)));
typedef float f32x4 __attribute__((ext_vector_type(4)));
typedef unsigned short ushort_t;

static __device__ __forceinline__ void lse_acc(float& m, float& s, float x) {
    float mn = fmaxf(m, x);
    s = s * __expf(m - mn) + __expf(x - mn);
    m = mn;
}
static __device__ __forceinline__ void lse_merge(float& m, float& s, float m2, float s2) {
    float mn = fmaxf(m, m2);
    s = s * __expf(m - mn) + s2 * __expf(m2 - mn);
    m = mn;
}
static __device__ __forceinline__ void lse_acc4(float4& m, float4& s, float4 x) {
    lse_acc(m.x, s.x, x.x);
    lse_acc(m.y, s.y, x.y);
    lse_acc(m.z, s.z, x.z);
    lse_acc(m.w, s.w, x.w);
}
// ---- single-__expf branchless online LSE (nat domain) ------------------------
static __device__ __forceinline__ void lse1_acc(float& m, float& s, float x) {
    float diff = x - m;
    float e = __expf(-fabsf(diff));        // v_mul(-|.|*log2e) + v_exp
    float a = __fmaf_rn(s, e, 1.0f);       // x > m: rescale old sum
    float b = s + e;                       // x <= m
    s = diff > 0.0f ? a : b;
    m = fmaxf(m, x);
}
static __device__ __forceinline__ void lse1_acc4(float4& m, float4& s, float4 x) {
    lse1_acc(m.x, s.x, x.x);
    lse1_acc(m.y, s.y, x.y);
    lse1_acc(m.z, s.z, x.z);
    lse1_acc(m.w, s.w, x.w);
}
static __device__ __forceinline__ void lse1_merge(float& m, float& s, float m2, float s2) {
    float diff = m2 - m;
    float e = __expf(-fabsf(diff));
    float a = __fmaf_rn(s, e, s2);         // m2 > m
    float b = __fmaf_rn(s2, e, s);         // m2 <= m
    s = diff > 0.0f ? a : b;
    m = fmaxf(m, m2);
}
static __device__ __forceinline__ int swz(int r, int k) {
    return k ^ (((r >> 3) & 7) << 2);
}
static __device__ __forceinline__ unsigned f2bf(float x) {
    unsigned u = __float_as_uint(x);
    return (u + 0x7FFF + ((u >> 16) & 1)) >> 16;   // RNE
}
static __device__ __forceinline__ float4 dec4(uint2 w, float stp, float bas) {
    float4 o;
    o.x = (float)(w.x & 0xFFFFu) * stp + bas;
    o.y = (float)(w.x >> 16)     * stp + bas;
    o.z = (float)(w.y & 0xFFFFu) * stp + bas;
    o.w = (float)(w.y >> 16)     * stp + bas;
    return o;
}
// split f32x4 -> hi bf16x4 + lo bf16x4 (packed)
static __device__ __forceinline__ uint2 packhl(float4 x, uint2& lo) {
    unsigned h0 = f2bf(x.x), h1 = f2bf(x.y), h2 = f2bf(x.z), h3 = f2bf(x.w);
    float r0 = x.x - __uint_as_float(h0 << 16);
    float r1 = x.y - __uint_as_float(h1 << 16);
    float r2 = x.z - __uint_as_float(h2 << 16);
    float r3 = x.w - __uint_as_float(h3 << 16);
    lo = make_uint2(f2bf(r0) | (f2bf(r1) << 16), f2bf(r2) | (f2bf(r3) << 16));
    return make_uint2(h0 | (h1 << 16), h2 | (h3 << 16));
}

// ---- zero u, v --------------------------------------------------------------
__global__ void k_init(float* u, float* v) {
    int i = blockIdx.x * 1024 + threadIdx.x;
    if (i < 8192) { u[i] = 0.0f; v[i] = 0.0f; }
}

// ---- squared norms ----------------------------------------------------------
__global__ __launch_bounds__(64) void k_sqnorm(const float* __restrict__ XP,
                                               const float* __restrict__ XQ,
                                               float* __restrict__ xx,
                                               float* __restrict__ yy) {
    int row = blockIdx.x;
    int lane = threadIdx.x;
    const float* src = (row < NN) ? (XP + (size_t)row * DD)
                                  : (XQ + (size_t)(row - NN) * DD);
    float2 w = *(const float2*)&src[lane * 2];
    float sres = w.x * w.x + w.y * w.y;
    #pragma unroll
    for (int off = 32; off > 0; off >>= 1)
        sres += __shfl_down(sres, off, 64);
    if (lane == 0) {
        if (row < NN) xx[row] = sres;
        else          yy[row - NN] = sres;
    }
}

// ---- XQT[d][m] = bf16(XQ[m][d]) ---------------------------------------------
__global__ __launch_bounds__(256) void k_xqt(const float* __restrict__ XQ,
                                             unsigned* __restrict__ XQT32) {
    __shared__ float As[32][129];
    int mb = blockIdx.x * 32;
    int t = threadIdx.x;
    int r = t >> 3, c0 = (t & 7) * 16;
    #pragma unroll
    for (int j = 0; j < 4; ++j)
        *(float4*)&As[r][c0 + j * 4] = *(const float4*)&XQ[(size_t)(mb + r) * DD + c0 + j * 4];
    __syncthreads();
    int d = t >> 1, p0 = (t & 1) * 8;
    #pragma unroll
    for (int j = 0; j < 8; ++j) {
        int pp = p0 + j;
        unsigned lo = f2bf(As[2 * pp][d]);
        unsigned hi = f2bf(As[2 * pp + 1][d]);
        XQT32[(size_t)d * 4096 + (mb >> 1) + pp] = lo | (hi << 16);
    }
}

// ---- MFMA Mr GEMM: Mr = -20*max(0, xx+yy-2*(hh+hl+lh)) ----------------------
__global__ __launch_bounds__(256, 2) void k_gemm_mr_mfma(const float* __restrict__ XP,
                                                         const float* __restrict__ XQ,
                                                         const float* __restrict__ xx,
                                                         const float* __restrict__ yy,
                                                         float* __restrict__ Mr) {
    __shared__ ushort_t Ah[128 * 64], Al[128 * 64];
    __shared__ ushort_t Bh[128 * 64], Bl[128 * 64];
    int rb = blockIdx.y * 128, cb = blockIdx.x * 128;
    int t = threadIdx.x;
    int w = t >> 6, lane = t & 63;
    int lane15 = lane & 15, lhi = lane >> 4;
    int wr = (w >> 1) * 64, wc = (w & 1) * 64;

    f32x4 acc00 = (f32x4)(0.f), acc01 = acc00, acc02 = acc00, acc03 = acc00;
    f32x4 acc10 = acc00, acc11 = acc00, acc12 = acc00, acc13 = acc00;
    f32x4 acc20 = acc00, acc21 = acc00, acc22 = acc00, acc23 = acc00;
    f32x4 acc30 = acc00, acc31 = acc00, acc32 = acc00, acc33 = acc00;

    for (int kc = 0; kc < 128; kc += 64) {
        __syncthreads();
        #pragma unroll
        for (int i = 0; i < 8; ++i) {
            int f = i * 256 + t;
            int r = f >> 4;
            int k4 = (f & 15) * 4;
            int g = k4 >> 3, hf = (k4 >> 2) & 1;
            int wa = r * 64 + ((g ^ (r & 7)) * 8 + hf * 4);
            float4 a = *(const float4*)&XP[(size_t)(rb + r) * DD + kc + k4];
            float4 b = *(const float4*)&XQ[(size_t)(cb + r) * DD + kc + k4];
            uint2 alo, blo;
            uint2 ahi = packhl(a, alo);
            uint2 bhi = packhl(b, blo);
            *(uint2*)&Ah[wa] = ahi; *(uint2*)&Al[wa] = alo;
            *(uint2*)&Bh[wa] = bhi; *(uint2*)&Bl[wa] = blo;
        }
        __syncthreads();
        #pragma unroll
        for (int ks = 0; ks < 2; ++ks) {
            int g = ks * 4 + lhi;
            bf16x8 ah[4], al[4], bh[4], bl[4];
            #pragma unroll
            for (int i = 0; i < 4; ++i) {
                int ar = wr + i * 16 + lane15;
                int ao = ar * 64 + ((g ^ (ar & 7)) * 8);
                ah[i] = *(bf16x8*)&Ah[ao];
                al[i] = *(bf16x8*)&Al[ao];
                int br = wc + i * 16 + lane15;
                int bo = br * 64 + ((g ^ (br & 7)) * 8);
                bh[i] = *(bf16x8*)&Bh[bo];
                bl[i] = *(bf16x8*)&Bl[bo];
            }
            #define MM3(AC, I, J) \
                AC = __builtin_amdgcn_mfma_f32_16x16x32_bf16(ah[I], bh[J], AC, 0, 0, 0); \
                AC = __builtin_amdgcn_mfma_f32_16x16x32_bf16(ah[I], bl[J], AC, 0, 0, 0); \
                AC = __builtin_amdgcn_mfma_f32_16x16x32_bf16(al[I], bh[J], AC, 0, 0, 0);
            MM3(acc00,0,0) MM3(acc01,0,1) MM3(acc02,0,2) MM3(acc03,0,3)
            MM3(acc10,1,0) MM3(acc11,1,1) MM3(acc12,1,2) MM3(acc13,1,3)
            MM3(acc20,2,0) MM3(acc21,2,1) MM3(acc22,2,2) MM3(acc23,2,3)
            MM3(acc30,3,0) MM3(acc31,3,1) MM3(acc32,3,2) MM3(acc33,3,3)
            #undef MM3
        }
    }
    float yv[4];
    #pragma unroll
    for (int j = 0; j < 4; ++j) yv[j] = yy[cb + wc + j * 16 + lane15];
    #define EPI(AC, I, J) { \
        _Pragma("unroll") \
        for (int reg = 0; reg < 4; ++reg) { \
            int gr = rb + wr + I * 16 + lhi * 4 + reg; \
            float C = xx[gr] + yv[J] - 2.f * AC[reg]; \
            Mr[(size_t)gr * MMX + cb + wc + J * 16 + lane15] = NEG20 * fmaxf(C, 0.f); \
        } }
    EPI(acc00,0,0) EPI(acc01,0,1) EPI(acc02,0,2) EPI(acc03,0,3)
    EPI(acc10,1,0) EPI(acc11,1,1) EPI(acc12,1,2) EPI(acc13,1,3)
    EPI(acc20,2,0) EPI(acc21,2,1) EPI(acc22,2,2) EPI(acc23,2,3)
    EPI(acc30,3,0) EPI(acc31,3,1) EPI(acc32,3,2) EPI(acc33,3,3)
    #undef EPI
}

// ---- f32 vector Mr GEMM (fallback paths only) --------------------------------
__global__ __launch_bounds__(256) void k_gemm_mr(const float* __restrict__ XP,
                                                 const float* __restrict__ XQ,
                                                 const float* __restrict__ xx,
                                                 const float* __restrict__ yy,
                                                 float* __restrict__ Mr) {
    __shared__ float As[128][64];
    __shared__ float Bs[128][64];
    int rb = blockIdx.y * 128, cb = blockIdx.x * 128;
    int t = threadIdx.x;
    int ty = t >> 4, tx = t & 15;
    int r0 = ty * 8, c0 = tx * 8;
    float acc[8][8] = {};

    for (int kc = 0; kc < 128; kc += 64) {
        __syncthreads();
        #pragma unroll
        for (int i = 0; i < 8; ++i) {
            int f = i * 256 + t;
            int r = f >> 4;
            int k4 = (f & 15) * 4;
            *(float4*)&As[r][swz(r, k4)] = *(const float4*)&XP[(size_t)(rb + r) * DD + kc + k4];
            *(float4*)&Bs[r][swz(r, k4)] = *(const float4*)&XQ[(size_t)(cb + r) * DD + kc + k4];
        }
        __syncthreads();
        for (int k = 0; k < 64; k += 4) {
            float4 a[8], b[8];
            #pragma unroll
            for (int i = 0; i < 8; ++i) {
                a[i] = *(float4*)&As[r0 + i][swz(r0 + i, k)];
                b[i] = *(float4*)&Bs[c0 + i][swz(c0 + i, k)];
            }
            #pragma unroll
            for (int i = 0; i < 8; ++i)
                #pragma unroll
                for (int j = 0; j < 8; ++j)
                    acc[i][j] += a[i].x * b[j].x + a[i].y * b[j].y +
                                 a[i].z * b[j].z + a[i].w * b[j].w;
        }
    }

    float yv[8];
    *(float4*)&yv[0] = *(const float4*)&yy[cb + c0];
    *(float4*)&yv[4] = *(const float4*)&yy[cb + c0 + 4];
    #pragma unroll
    for (int i = 0; i < 8; ++i) {
        int gr = rb + r0 + i;
        float xxi = xx[gr];
        float4 o0, o1;
        o0.x = NEG20 * fmaxf(xxi + yv[0] - 2.f * acc[i][0], 0.f);
        o0.y = NEG20 * fmaxf(xxi + yv[1] - 2.f * acc[i][1], 0.f);
        o0.z = NEG20 * fmaxf(xxi + yv[2] - 2.f * acc[i][2], 0.f);
        o0.w = NEG20 * fmaxf(xxi + yv[3] - 2.f * acc[i][3], 0.f);
        o1.x = NEG20 * fmaxf(xxi + yv[4] - 2.f * acc[i][4], 0.f);
        o1.y = NEG20 * fmaxf(xxi + yv[5] - 2.f * acc[i][5], 0.f);
        o1.z = NEG20 * fmaxf(xxi + yv[6] - 2.f * acc[i][6], 0.f);
        o1.w = NEG20 * fmaxf(xxi + yv[7] - 2.f * acc[i][7], 0.f);
        *(float4*)&Mr[(size_t)gr * MMX + cb + c0] = o0;
        *(float4*)&Mr[(size_t)gr * MMX + cb + c0 + 4] = o1;
    }
}

// ---- quantize Mr row -> in-slot int16 + (base,step) --------------------------
__global__ __launch_bounds__(256) void k_quant(float* __restrict__ Mr) {
    float* slot = Mr + (size_t)blockIdx.x * MMX;
    int t = threadIdx.x;
    float4 x[8];
    float mn = 1e30f, mx = -1e30f;
    #pragma unroll
    for (int i = 0; i < 8; ++i) {
        x[i] = *(const float4*)&slot[(t + 256 * i) * 4];
        mn = fminf(mn, fminf(fminf(x[i].x, x[i].y), fminf(x[i].z, x[i].w)));
        mx = fmaxf(mx, fmaxf(fmaxf(x[i].x, x[i].y), fmaxf(x[i].z, x[i].w)));
    }
    #pragma unroll
    for (int off = 32; off > 0; off >>= 1) {
        mn = fminf(mn, __shfl_xor(mn, off));
        mx = fmaxf(mx, __shfl_xor(mx, off));
    }
    __shared__ float smn[4], smx[4];
    int wid = t >> 6;
    if ((t & 63) == 0) { smn[wid] = mn; smx[wid] = mx; }
    __syncthreads();
    mn = fminf(fminf(smn[0], smn[1]), fminf(smn[2], smn[3]));
    mx = fmaxf(fmaxf(smx[0], smx[1]), fmaxf(smx[2], smx[3]));
    float span = fmaxf(mx - mn, 1e-20f);
    float inv = 65535.0f / span;
    float stp = span * (1.0f / 65535.0f);
    uint2* out16 = (uint2*)slot;
    #pragma unroll
    for (int i = 0; i < 8; ++i) {
        unsigned q0 = (unsigned)fminf(rintf((x[i].x - mn) * inv), 65535.f);
        unsigned q1 = (unsigned)fminf(rintf((x[i].y - mn) * inv), 65535.f);
        unsigned q2 = (unsigned)fminf(rintf((x[i].z - mn) * inv), 65535.f);
        unsigned q3 = (unsigned)fminf(rintf((x[i].w - mn) * inv), 65535.f);
        out16[t + 256 * i] = make_uint2(q0 | (q1 << 16), q2 | (q3 << 16));
    }
    if (t == 0) *(float2*)&slot[4096] = make_float2(mn, stp);
}

// ---- column-LSE partial: (8,128) grid, 1024c x 64r, 1-exp LSE ----------------
__global__ __launch_bounds__(256) void k_colpass_q64(const float* __restrict__ Mr,
                                                     const float* __restrict__ u,
                                                     float* __restrict__ part) {
    int c = blockIdx.x * 1024 + threadIdx.x * 4;
    int n0 = blockIdx.y * 64;
    float4 mx = make_float4(-1e30f, -1e30f, -1e30f, -1e30f);
    float4 s = make_float4(0.f, 0.f, 0.f, 0.f);
    #pragma unroll 8
    for (int r = 0; r < 64; ++r) {
        const float* slot = Mr + (size_t)(n0 + r) * MMX;
        float2 bs = *(const float2*)&slot[4096];
        float basu = bs.x + u[n0 + r];
        uint2 w = *(const uint2*)((const ushort_t*)slot + c);
        lse1_acc4(mx, s, dec4(w, bs.y, basu));
    }
    float4 o;
    o.x = mx.x + __logf(s.x);
    o.y = mx.y + __logf(s.y);
    o.z = mx.z + __logf(s.z);
    o.w = mx.w + __logf(s.w);
    *(float4*)&part[(size_t)blockIdx.y * MMX + c] = o;
}

// ---- combine 128 chunk-LSEs -> v[m]: 128 blocks, 4-way split chain -----------
__global__ __launch_bounds__(256) void k_colcombine4(const float* __restrict__ part,
                                                     float* __restrict__ v) {
    int t = threadIdx.x;
    int col = blockIdx.x * 64 + (t & 63);
    int q = t >> 6;
    float mx = -1e30f, s = 0.f;
    #pragma unroll 8
    for (int ch = 0; ch < 32; ++ch)
        lse1_acc(mx, s, part[(size_t)(q * 32 + ch) * MMX + col]);
    __shared__ float sm[4][64], ss[4][64];
    sm[q][t & 63] = mx; ss[q][t & 63] = s;
    __syncthreads();
    if (q == 0) {
        lse1_merge(mx, s, sm[1][t], ss[1][t]);
        lse1_merge(mx, s, sm[2][t], ss[2][t]);
        lse1_merge(mx, s, sm[3][t], ss[3][t]);
        v[col] = LOGAB - (mx + __logf(s));
    }
}

// ---- row-LSE: 1024 blocks x 8 rows, 1-exp LSE --------------------------------
__global__ __launch_bounds__(256) void k_rowpass_q(const float* __restrict__ Mr,
                                                   const float* __restrict__ v,
                                                   float* __restrict__ u) {
    int n0 = blockIdx.x * 8;
    int t = threadIdx.x;
    float basr[8], stpr[8];
    const ushort_t* us[8];
    #pragma unroll
    for (int r = 0; r < 8; ++r) {
        const float* slot = Mr + (size_t)(n0 + r) * MMX;
        float2 bs = *(const float2*)&slot[4096];
        basr[r] = bs.x;
        stpr[r] = bs.y;
        us[r] = (const ushort_t*)slot;
    }
    float4 mx[8], s[8];
    #pragma unroll
    for (int r = 0; r < 8; ++r) {
        mx[r] = make_float4(-1e30f, -1e30f, -1e30f, -1e30f);
        s[r] = make_float4(0.f, 0.f, 0.f, 0.f);
    }
    const float4* v4 = (const float4*)v;
    for (int i = t; i < MMX / 4; i += 256) {
        float4 vv = v4[i];
        #pragma unroll
        for (int r = 0; r < 8; ++r) {
            uint2 w = *(const uint2*)&us[r][i * 4];
            float4 d = dec4(w, stpr[r], basr[r]);
            d.x += vv.x; d.y += vv.y; d.z += vv.z; d.w += vv.w;
            lse1_acc4(mx[r], s[r], d);
        }
    }
    __shared__ float smm[8][4], sss[8][4];
    int wid = t >> 6, lane = t & 63;
    #pragma unroll
    for (int r = 0; r < 8; ++r) {
        float m1 = mx[r].x, s1 = s[r].x;
        lse1_merge(m1, s1, mx[r].y, s[r].y);
        lse1_merge(m1, s1, mx[r].z, s[r].z);
        lse1_merge(m1, s1, mx[r].w, s[r].w);
        #pragma unroll
        for (int off = 32; off > 0; off >>= 1) {
            float m2 = __shfl_xor(m1, off);
            float s2 = __shfl_xor(s1, off);
            lse1_merge(m1, s1, m2, s2);
        }
        if (lane == 0) { smm[r][wid] = m1; sss[r][wid] = s1; }
    }
    __syncthreads();
    if (t < 8) {
        float m1 = smm[t][0], s1 = sss[t][0];
        lse1_merge(m1, s1, smm[t][1], sss[t][1]);
        lse1_merge(m1, s1, smm[t][2], sss[t][2]);
        lse1_merge(m1, s1, smm[t][3], sss[t][3]);
        u[n0 + t] = LOGAB - (m1 + __logf(s1));
    }
}

// ---- f32 colpass/combine/rowpass (fallback paths) ----------------------------
__global__ __launch_bounds__(256) void k_colpass(const float* __restrict__ Mr,
                                                 const float* __restrict__ u,
                                                 float* __restrict__ part) {
    int c = blockIdx.x * 1024 + threadIdx.x * 4;
    int n0 = blockIdx.y * 128;
    float4 mx = make_float4(-1e30f, -1e30f, -1e30f, -1e30f);
    float4 s = make_float4(0.f, 0.f, 0.f, 0.f);
    #pragma unroll 8
    for (int r = 0; r < 128; ++r) {
        float un = u[n0 + r];
        float4 w = *(const float4*)&Mr[(size_t)(n0 + r) * MMX + c];
        w.x += un; w.y += un; w.z += un; w.w += un;
        lse_acc4(mx, s, w);
    }
    float4 o;
    o.x = mx.x + __logf(s.x);
    o.y = mx.y + __logf(s.y);
    o.z = mx.z + __logf(s.z);
    o.w = mx.w + __logf(s.w);
    *(float4*)&part[(size_t)blockIdx.y * MMX + c] = o;
}

__global__ __launch_bounds__(256) void k_colcombine(const float* __restrict__ part,
                                                    float* __restrict__ v) {
    int m = blockIdx.x * 256 + threadIdx.x;
    float mx = -1e30f, s = 0.f;
    #pragma unroll 8
    for (int ch = 0; ch < 64; ++ch)
        lse_acc(mx, s, part[(size_t)ch * MMX + m]);
    v[m] = LOGAB - (mx + __logf(s));
}

__global__ __launch_bounds__(256) void k_rowpass(const float* __restrict__ Mr,
                                                 const float* __restrict__ v,
                                                 float* __restrict__ u) {
    int n0 = blockIdx.x * 8;
    int t = threadIdx.x;
    float4 mx[8], s[8];
    #pragma unroll
    for (int r = 0; r < 8; ++r) {
        mx[r] = make_float4(-1e30f, -1e30f, -1e30f, -1e30f);
        s[r] = make_float4(0.f, 0.f, 0.f, 0.f);
    }
    const float4* v4 = (const float4*)v;
    for (int i = t; i < MMX / 4; i += 256) {
        float4 vv = v4[i];
        #pragma unroll
        for (int r = 0; r < 8; ++r) {
            float4 w = *(const float4*)&Mr[(size_t)(n0 + r) * MMX + i * 4];
            w.x += vv.x; w.y += vv.y; w.z += vv.z; w.w += vv.w;
            lse_acc4(mx[r], s[r], w);
        }
    }
    __shared__ float smm[8][4], sss[8][4];
    int wid = t >> 6, lane = t & 63;
    #pragma unroll
    for (int r = 0; r < 8; ++r) {
        float m1 = mx[r].x, s1 = s[r].x;
        lse_merge(m1, s1, mx[r].y, s[r].y);
        lse_merge(m1, s1, mx[r].z, s[r].z);
        lse_merge(m1, s1, mx[r].w, s[r].w);
        #pragma unroll
        for (int off = 32; off > 0; off >>= 1) {
            float m2 = __shfl_xor(m1, off);
            float s2 = __shfl_xor(s1, off);
            lse_merge(m1, s1, m2, s2);
        }
        if (lane == 0) { smm[r][wid] = m1; sss[r][wid] = s1; }
    }
    __syncthreads();
    if (t < 8) {
        float m1 = smm[t][0], s1 = sss[t][0];
        lse_merge(m1, s1, smm[t][1], sss[t][1]);
        lse_merge(m1, s1, smm[t][2], sss[t][2]);
        lse_merge(m1, s1, smm[t][3], sss[t][3]);
        u[n0 + t] = LOGAB - (m1 + __logf(s1));
    }
}

// ---- MFMA FUSED (round-8 proven): 512 blk x 256 thr x 16 rows ----------------
__global__ __launch_bounds__(256) void k_pi_mapped_mfma_q(float* __restrict__ P,
                                                          const unsigned* __restrict__ XQT32,
                                                          const float* __restrict__ u,
                                                          const float* __restrict__ v,
                                                          float* __restrict__ mapped) {
    __shared__ unsigned short PIs[16 * 64];
    __shared__ unsigned short QTs[128 * 64];
    int r0 = blockIdx.x * 16;
    int t = threadIdx.x;                 // 0..255
    int wid = t >> 6, lane = t & 63;
    int lane15 = lane & 15, lhi = lane >> 4;
    int dbase = wid * 32;
    int prow = t >> 4;
    int pm4 = (t & 15) * 4;
    int pgran = (t & 15) >> 1, phalf = t & 1;
    int qd = t >> 1;
    int qg0 = (t & 1) * 4;

    float* slotp = P + (size_t)(r0 + prow) * MMX;
    const ushort_t* usp = (const ushort_t*)slotp;
    float2 bs = *(const float2*)&slotp[4096];
    float stp = bs.y;
    float basu = bs.x + u[r0 + prow];

    f32x4 acc[2];
    acc[0] = (f32x4)(0.f);
    acc[1] = (f32x4)(0.f);

    int mb0 = MMX - 64;
    uint2 pq = *(const uint2*)&usp[mb0 + pm4];
    float4 vv = *(const float4*)&v[mb0 + pm4];
    uint4 xq0 = *(const uint4*)&XQT32[(size_t)qd * 4096 + (mb0 >> 1) + qg0 * 4];
    uint4 xq1 = *(const uint4*)&XQT32[(size_t)qd * 4096 + (mb0 >> 1) + qg0 * 4 + 4];
    uint4 xq2 = *(const uint4*)&XQT32[(size_t)qd * 4096 + (mb0 >> 1) + qg0 * 4 + 8];
    uint4 xq3 = *(const uint4*)&XQT32[(size_t)qd * 4096 + (mb0 >> 1) + qg0 * 4 + 12];

    for (int mb = mb0; mb >= 0; mb -= 64) {
        __syncthreads();
        float4 d = dec4(pq, stp, basu);
        float4 w;
        w.x = __expf(d.x + vv.x);
        w.y = __expf(d.y + vv.y);
        w.z = __expf(d.z + vv.z);
        w.w = __expf(d.w + vv.w);
        uint2 pk;
        pk.x = f2bf(w.x) | (f2bf(w.y) << 16);
        pk.y = f2bf(w.z) | (f2bf(w.w) << 16);
        *(uint2*)&PIs[prow * 64 + (pgran ^ (prow & 7)) * 8 + phalf * 4] = pk;
        *(uint4*)&QTs[qd * 64 + ((qg0 + 0) ^ (qd & 7)) * 8] = xq0;
        *(uint4*)&QTs[qd * 64 + ((qg0 + 1) ^ (qd & 7)) * 8] = xq1;
        *(uint4*)&QTs[qd * 64 + ((qg0 + 2) ^ (qd & 7)) * 8] = xq2;
        *(uint4*)&QTs[qd * 64 + ((qg0 + 3) ^ (qd & 7)) * 8] = xq3;
        __syncthreads();
        *(float4*)&slotp[mb + pm4] = w;
        if (mb > 0) {
            int nb = mb - 64;
            pq = *(const uint2*)&usp[nb + pm4];
            vv = *(const float4*)&v[nb + pm4];
            xq0 = *(const uint4*)&XQT32[(size_t)qd * 4096 + (nb >> 1) + qg0 * 4];
            xq1 = *(const uint4*)&XQT32[(size_t)qd * 4096 + (nb >> 1) + qg0 * 4 + 4];
            xq2 = *(const uint4*)&XQT32[(size_t)qd * 4096 + (nb >> 1) + qg0 * 4 + 8];
            xq3 = *(const uint4*)&XQT32[(size_t)qd * 4096 + (nb >> 1) + qg0 * 4 + 12];
        }
        bf16x8 afr[2];
        #pragma unroll
        for (int ks = 0; ks < 2; ++ks) {
            int g = ks * 4 + lhi;
            afr[ks] = *(bf16x8*)&PIs[lane15 * 64 + (g ^ (lane15 & 7)) * 8];
        }
        #pragma unroll
        for (int dt = 0; dt < 2; ++dt) {
            int drow = dbase + dt * 16 + lane15;
            #pragma unroll
            for (int ks = 0; ks < 2; ++ks) {
                int g = ks * 4 + lhi;
                bf16x8 bfr = *(bf16x8*)&QTs[drow * 64 + (g ^ (drow & 7)) * 8];
                acc[dt] = __builtin_amdgcn_mfma_f32_16x16x32_bf16(afr[ks], bfr, acc[dt], 0, 0, 0);
            }
        }
    }
    #pragma unroll
    for (int dt = 0; dt < 2; ++dt) {
        int dcol = dbase + dt * 16 + lane15;
        #pragma unroll
        for (int reg = 0; reg < 4; ++reg) {
            int nrow = r0 + lhi * 4 + reg;
            mapped[(size_t)nrow * DD + dcol] = acc[dt][reg] * 8192.f;
        }
    }
}

// ---- vector FUSED (mid-ws path, f32 Mr) --------------------------------------
__global__ __launch_bounds__(512, 1) void k_pi_mapped(float* __restrict__ P,
                                                      const float* __restrict__ XQ,
                                                      const float* __restrict__ u,
                                                      const float* __restrict__ v,
                                                      float* __restrict__ mapped) {
    __shared__ float PIs[32][68];
    __shared__ float QS[64][128];
    int r0 = blockIdx.x * 32;
    int t = threadIdx.x;
    int tid = t & 255;
    int half = t >> 8;
    int rg = tid >> 5;
    int dg = tid & 31;
    int prow = t >> 4;
    int pc4 = (t & 15) * 4;
    int qrb = t >> 5;
    int qc4 = (t & 31) * 4;
    float urow = u[r0 + prow];

    float4 acc[4];
    acc[0] = acc[1] = acc[2] = acc[3] = make_float4(0.f, 0.f, 0.f, 0.f);

    float4 pw, vv, xq0, xq1, xq2, xq3;
    pw = *(const float4*)&P[(size_t)(r0 + prow) * MMX + pc4];
    vv = *(const float4*)&v[pc4];
    xq0 = *(const float4*)&XQ[(size_t)(qrb) * DD + qc4];
    xq1 = *(const float4*)&XQ[(size_t)(16 + qrb) * DD + qc4];
    xq2 = *(const float4*)&XQ[(size_t)(32 + qrb) * DD + qc4];
    xq3 = *(const float4*)&XQ[(size_t)(48 + qrb) * DD + qc4];

    for (int mb = 0; mb < MMX; mb += 64) {
        __syncthreads();
        float4 w;
        w.x = __expf(pw.x + urow + vv.x);
        w.y = __expf(pw.y + urow + vv.y);
        w.z = __expf(pw.z + urow + vv.z);
        w.w = __expf(pw.w + urow + vv.w);
        *(float4*)&PIs[prow][pc4] = w;
        *(float4*)&QS[qrb][qc4] = xq0;
        *(float4*)&QS[16 + qrb][qc4] = xq1;
        *(float4*)&QS[32 + qrb][qc4] = xq2;
        *(float4*)&QS[48 + qrb][qc4] = xq3;
        __syncthreads();
        *(float4*)&P[(size_t)(r0 + prow) * MMX + mb + pc4] = w;
        if (mb + 64 < MMX) {
            int nb = mb + 64;
            pw = *(const float4*)&P[(size_t)(r0 + prow) * MMX + nb + pc4];
            vv = *(const float4*)&v[nb + pc4];
            xq0 = *(const float4*)&XQ[(size_t)(nb + qrb) * DD + qc4];
            xq1 = *(const float4*)&XQ[(size_t)(nb + 16 + qrb) * DD + qc4];
            xq2 = *(const float4*)&XQ[(size_t)(nb + 32 + qrb) * DD + qc4];
            xq3 = *(const float4*)&XQ[(size_t)(nb + 48 + qrb) * DD + qc4];
        }
        #pragma unroll
        for (int sstep = 0; sstep < 8; ++sstep) {
            int k = (half * 8 + sstep) * 4;
            float4 q0 = *(float4*)&QS[k + 0][dg * 4];
            float4 q1 = *(float4*)&QS[k + 1][dg * 4];
            float4 q2 = *(float4*)&QS[k + 2][dg * 4];
            float4 q3 = *(float4*)&QS[k + 3][dg * 4];
            #pragma unroll
            for (int j = 0; j < 4; ++j) {
                float4 p = *(float4*)&PIs[rg * 4 + j][k];
                acc[j].x += p.x * q0.x + p.y * q1.x + p.z * q2.x + p.w * q3.x;
                acc[j].y += p.x * q0.y + p.y * q1.y + p.z * q2.y + p.w * q3.y;
                acc[j].z += p.x * q0.z + p.y * q1.z + p.z * q2.z + p.w * q3.z;
                acc[j].w += p.x * q0.w + p.y * q1.w + p.z * q2.w + p.w * q3.w;
            }
        }
    }
    __syncthreads();
    float* mrg = &QS[0][0];
    if (half == 1) {
        #pragma unroll
        for (int j = 0; j < 4; ++j)
            *(float4*)&mrg[tid * 16 + j * 4] = acc[j];
    }
    __syncthreads();
    if (half == 0) {
        #pragma unroll
        for (int j = 0; j < 4; ++j) {
            float4 o = *(const float4*)&mrg[tid * 16 + j * 4];
            o.x = (acc[j].x + o.x) * 8192.f;
            o.y = (acc[j].y + o.y) * 8192.f;
            o.z = (acc[j].z + o.z) * 8192.f;
            o.w = (acc[j].w + o.w) * 8192.f;
            *(float4*)&mapped[(size_t)(r0 + rg * 4 + j) * DD + dg * 4] = o;
        }
    }
}

// ---- fallback (tiny ws): separate pi / mapped --------------------------------
__global__ __launch_bounds__(256) void k_pi(float* __restrict__ Mr,
                                            const float* __restrict__ u,
                                            const float* __restrict__ v) {
    const float4* v4 = (const float4*)v;
    for (int i = blockIdx.x * 256 + threadIdx.x; i < NN * MMX / 4; i += 2048 * 256) {
        int n = i >> 11;
        int m4 = i & 2047;
        float un = u[n];
        float4 vv = v4[m4];
        float4* p = (float4*)Mr + i;
        float4 w = *p;
        w.x = __expf(w.x + un + vv.x);
        w.y = __expf(w.y + un + vv.y);
        w.z = __expf(w.z + un + vv.z);
        w.w = __expf(w.w + un + vv.w);
        *p = w;
    }
}

__global__ __launch_bounds__(256) void k_mapped(const float* __restrict__ pi,
                                                const float* __restrict__ XQ,
                                                float* __restrict__ mapped) {
    __shared__ float XQs[64][128];
    __shared__ float PIs[32][64];
    int r0 = blockIdx.x * 32;
    int t = threadIdx.x;
    int dg = (t & 31) * 4;
    int rg = (t >> 5) * 4;
    float4 acc[4];
    #pragma unroll
    for (int j = 0; j < 4; ++j) acc[j] = make_float4(0.f, 0.f, 0.f, 0.f);

    for (int mb = 0; mb < MMX; mb += 64) {
        __syncthreads();
        #pragma unroll
        for (int i = 0; i < 8; ++i) {
            int f = i * 256 + t;
            int rr = f >> 5;
            int k4 = (f & 31) * 4;
            *(float4*)&XQs[rr][k4] = *(const float4*)&XQ[(size_t)(mb + rr) * DD + k4];
        }
        #pragma unroll
        for (int i = 0; i < 2; ++i) {
            int f = i * 256 + t;
            int rr = f >> 4;
            int c4 = (f & 15) * 4;
            *(float4*)&PIs[rr][c4] = *(const float4*)&pi[(size_t)(r0 + rr) * MMX + mb + c4];
        }
        __syncthreads();
        for (int mm = 0; mm < 64; mm += 4) {
            float4 q0 = *(float4*)&XQs[mm + 0][dg];
            float4 q1 = *(float4*)&XQs[mm + 1][dg];
            float4 q2 = *(float4*)&XQs[mm + 2][dg];
            float4 q3 = *(float4*)&XQs[mm + 3][dg];
            #pragma unroll
            for (int j = 0; j < 4; ++j) {
                float4 p = *(float4*)&PIs[rg + j][mm];
                acc[j].x += p.x * q0.x + p.y * q1.x + p.z * q2.x + p.w * q3.x;
                acc[j].y += p.x * q0.y + p.y * q1.y + p.z * q2.y + p.w * q3.y;
                acc[j].z += p.x * q0.z + p.y * q1.z + p.z * q2.z + p.w * q3.z;
                acc[j].w += p.x * q0.w + p.y * q1.w + p.z * q2.w + p.w * q3.w;
            }
        }
    }
    #pragma unroll
    for (int j = 0; j < 4; ++j) {
        float4 o = acc[j];
        o.x *= 8192.f; o.y *= 8192.f; o.z *= 8192.f; o.w *= 8192.f;
        *(float4*)&mapped[(size_t)(r0 + rg + j) * DD + dg] = o;
    }
}

extern "C" void kernel_launch(void* const* d_in, const int* in_sizes, int n_in,
                              void* d_out, int out_size, void* d_ws, size_t ws_size,
                              hipStream_t stream) {
    const float* XP = (const float*)d_in[0];
    const float* XQ = (const float*)d_in[1];
    float* out = (float*)d_out;
    float* Mr = out + (size_t)NN * DD;            // pi region: Mr / Mrq / pi

    bool big = (ws_size >= 2228224);              // XQT(2 MiB) + u/v/xx/yy
    bool mid = (ws_size >= 131072);
    unsigned* XQT32 = big ? (unsigned*)d_ws : nullptr;
    float* wsf = big ? (float*)((char*)d_ws + 2097152) : (float*)d_ws;
    float* u  = mid ? wsf           : out;
    float* v  = mid ? wsf + 8192    : out + 8192;
    float* xx = mid ? wsf + 16384   : out + 40960;
    float* yy = mid ? wsf + 24576   : out + 49152;
    float* part_big = out;                        // 128 x 8192 (4 MiB, mapped region)
    float* part_mid = out + 65536;                // 64 x 8192 (fallback layout)

    k_init<<<8, 1024, 0, stream>>>(u, v);
    k_sqnorm<<<NN + MMX, 64, 0, stream>>>(XP, XQ, xx, yy);
    if (big) {
        k_gemm_mr_mfma<<<dim3(64, 64), 256, 0, stream>>>(XP, XQ, xx, yy, Mr);
        k_xqt<<<256, 256, 0, stream>>>(XQ, XQT32);
        k_quant<<<8192, 256, 0, stream>>>(Mr);
    } else {
        k_gemm_mr<<<dim3(64, 64), 256, 0, stream>>>(XP, XQ, xx, yy, Mr);
    }

    for (int it = 0; it < NITER; ++it) {
        if (big) {
            k_colpass_q64<<<dim3(8, 128), 256, 0, stream>>>(Mr, u, part_big);
            k_colcombine4<<<128, 256, 0, stream>>>(part_big, v);
            k_rowpass_q<<<1024, 256, 0, stream>>>(Mr, v, u);
        } else {
            k_colpass<<<dim3(8, 64), 256, 0, stream>>>(Mr, u, part_mid);
            k_colcombine<<<32, 256, 0, stream>>>(part_mid, v);
            k_rowpass<<<1024, 256, 0, stream>>>(Mr, v, u);
        }
    }

    if (big) {
        k_pi_mapped_mfma_q<<<512, 256, 0, stream>>>(Mr, XQT32, u, v, out);
    } else if (mid) {
        k_pi_mapped<<<256, 512, 0, stream>>>(Mr, XQ, u, v, out);
    } else {
        k_pi<<<2048, 256, 0, stream>>>(Mr, u, v);
        k_mapped<<<256, 256, 0, stream>>>(Mr, XQ, out);
    }
}